// Round 3
// baseline (1101.313 us; speedup 1.0000x reference)
//
#include <hip/hip_runtime.h>
#include <hip/hip_bf16.h>

typedef unsigned short u16;
typedef __bf16 bf16x8v __attribute__((ext_vector_type(8)));
typedef float f32x4v __attribute__((ext_vector_type(4)));
typedef float f32x4u __attribute__((ext_vector_type(4))) __attribute__((aligned(4)));

// ---------- bf16 helpers (RNE) ----------
__device__ __forceinline__ float bf2f(u16 u) {
    union { float f; unsigned int i; } c; c.i = ((unsigned int)u) << 16; return c.f;
}
__device__ __forceinline__ u16 f2bf(float f) {
    union { float f; unsigned int i; } c; c.f = f;
    unsigned int i = c.i;
    unsigned int lsb = (i >> 16) & 1u;
    i += 0x7fffu + lsb;
    return (u16)(i >> 16);
}
__device__ __forceinline__ float lo16(unsigned u) { return bf2f((u16)(u & 0xffff)); }
__device__ __forceinline__ float hi16(unsigned u) { return bf2f((u16)(u >> 16)); }
__device__ __forceinline__ unsigned pack2(float lo, float hi) {
    return (unsigned)f2bf(lo) | ((unsigned)f2bf(hi) << 16);
}

// packed-bf16 bit tricks (2 elements per u32, no float round-trip):
//   neg2:      x -> -x           (sign flip both halves)
//   relu2:     x -> relu(x)      (negative halves -> 0)
//   relu_neg2: x -> -relu(x)
__device__ __forceinline__ unsigned neg2(unsigned u) { return u ^ 0x80008000u; }
__device__ __forceinline__ unsigned relu2(unsigned u) {
    unsigned s = u & 0x80008000u;
    unsigned m = (s - (s >> 15)) | s;      // 0xffff per negative half
    return u & ~m;
}
__device__ __forceinline__ unsigned relu_neg2(unsigned u) {
    unsigned s = u & 0x80008000u;
    unsigned m = (s - (s >> 15)) | s;
    return (u ^ 0x80008000u) & ~m;
}

// load 8 fp32 from rowp[k..k+7] (guarded, zero-padded), convert to bf16x8 fragment
__device__ __forceinline__ bf16x8v load_cvt8(const float* __restrict__ rowp, int k, int kmax) {
    union { unsigned u[4]; bf16x8v v; } r;
#pragma unroll
    for (int g = 0; g < 2; ++g) {
        int kk = k + g * 4;
        float f0, f1, f2, f3;
        if (kk + 3 < kmax) {
            f32x4u q = *(const f32x4u*)(rowp + kk);
            f0 = q.x; f1 = q.y; f2 = q.z; f3 = q.w;
        } else {
            f0 = (kk + 0 < kmax) ? rowp[kk + 0] : 0.f;
            f1 = (kk + 1 < kmax) ? rowp[kk + 1] : 0.f;
            f2 = (kk + 2 < kmax) ? rowp[kk + 2] : 0.f;
            f3 = (kk + 3 < kmax) ? rowp[kk + 3] : 0.f;
        }
        r.u[g * 2]     = pack2(f0, f1);
        r.u[g * 2 + 1] = pack2(f2, f3);
    }
    return r.v;
}

// ---------- weight packing: Wt[n][k] = W[k][n], K padded with zeros ----------
__global__ void pack_w(const float* __restrict__ W, u16* __restrict__ Wt, int K, int Kpad) {
    int idx = blockIdx.x * 256 + threadIdx.x;
    if (idx >= 256 * Kpad) return;
    int n = idx / Kpad, k = idx % Kpad;
    float v = (k < K) ? W[k * 256 + n] : 0.f;
    Wt[idx] = f2bf(v);
}

// W_o packed for reordered concat: a_input = [a_message(256) | f_atoms(133) | pad(to 448)]
__global__ void pack_wo(const float* __restrict__ W_o, u16* __restrict__ Wt) {
    int idx = blockIdx.x * 256 + threadIdx.x;
    if (idx >= 256 * 448) return;
    int n = idx / 448, k = idx % 448;
    float v;
    if (k < 256)       v = W_o[(133 + k) * 256 + n];
    else if (k < 389)  v = W_o[(k - 256) * 256 + n];
    else               v = 0.f;
    Wt[idx] = f2bf(v);
}

// ---------- GEMM1: inp = f_bonds(fp32, stride 147) @ W_i^T, conversion fused into A-load ----------
__global__ __launch_bounds__(512, 2)
void gemm_in(const float* __restrict__ A, const u16* __restrict__ Bt, int M,
             u16* __restrict__ out0) {
    constexpr int KPAD = 160, KMAX = 147, ASTR = 147;
    constexpr int LSTR = KPAD + 8;
    __shared__ u16 Bs[256 * LSTR];
    const int tid = threadIdx.x;
    const int wave = tid >> 6;
    const int lane = tid & 63;
    const int mrow = lane & 15;
    const int quad = lane >> 4;

    constexpr int KC = KPAD / 8;
    for (int i = tid; i < 256 * KC; i += 512) {
        int r = i / KC, kc = i % KC;
        *(uint4*)&Bs[r * LSTR + kc * 8] = *(const uint4*)&Bt[(size_t)r * KPAD + kc * 8];
    }
    __syncthreads();

    for (long chunk = blockIdx.x; chunk * 256 < (long)M; chunk += gridDim.x) {
        const long mbase = chunk * 256 + wave * 32;
        const float* rowp[2];
#pragma unroll
        for (int t = 0; t < 2; ++t) {
            long r = mbase + t * 16 + mrow;
            if (r >= M) r = M - 1;
            rowp[t] = A + r * ASTR;
        }

        f32x4v acc[2][16];
#pragma unroll
        for (int t = 0; t < 2; ++t)
#pragma unroll
            for (int j = 0; j < 16; ++j) acc[t][j] = (f32x4v){0.f, 0.f, 0.f, 0.f};

#pragma unroll 2
        for (int k0 = 0; k0 < KPAD; k0 += 32) {
            bf16x8v a_frag[2];
#pragma unroll
            for (int t = 0; t < 2; ++t)
                a_frag[t] = load_cvt8(rowp[t], k0 + quad * 8, KMAX);
#pragma unroll
            for (int jg = 0; jg < 4; ++jg) {
                bf16x8v b_frag[4];
#pragma unroll
                for (int j4 = 0; j4 < 4; ++j4)
                    b_frag[j4] = *(const bf16x8v*)&Bs[((jg * 4 + j4) * 16 + mrow) * LSTR + k0 + quad * 8];
#pragma unroll
                for (int t = 0; t < 2; ++t)
#pragma unroll
                    for (int j4 = 0; j4 < 4; ++j4)
                        acc[t][jg * 4 + j4] = __builtin_amdgcn_mfma_f32_16x16x32_bf16(
                            a_frag[t], b_frag[j4], acc[t][jg * 4 + j4], 0, 0, 0);
            }
        }

#pragma unroll
        for (int t = 0; t < 2; ++t)
#pragma unroll
            for (int r = 0; r < 4; ++r) {
                long grow = mbase + t * 16 + quad * 4 + r;
                if (grow < M)
#pragma unroll
                    for (int j = 0; j < 16; ++j)
                        out0[(size_t)grow * 256 + j * 16 + mrow] = f2bf(acc[t][j][r]);
            }
    }
}

// ---------- fused message-passing GEMM (gather-on-the-fly, N-split, dual-MFMA, XCD-paired) ----------
// msg_new[b][:] = relu( inp[b] + (sum_j w_j*relu?(msg[a2b[b2a[b],j]]) - relu?(msg_rev[b2revb[b]])) @ Wh^T )
// The per-atom gather (was gather16 + materialized amsg) is computed on the fly per bond:
// 6 gathered rows weighted-summed in fp32 -> bf16 a1 frag (same rounding point as materialized amsg);
// rev row via packed bit-trick -> a2 frag; dual MFMA. Eliminates the gather16 dispatch and
// amsg HBM round-trip per iteration.
// Wave = 16 bonds x 128 cols (acc 32 regs -> <=128 VGPR -> 2 blocks/CU = 16 waves).
// XCD-paired N-halves (round-2 proven) so the duplicate half's gathered rows L2-hit.
template <bool RELUV>
__global__ __launch_bounds__(512, 4)
void gemm_mp(const u16* __restrict__ msg, const int* __restrict__ a2b,
             const int* __restrict__ b2a, const int* __restrict__ b2revb,
             const float* __restrict__ w_bonds, const u16* __restrict__ Bt,
             int M, const u16* __restrict__ inp, u16* __restrict__ out0) {
    constexpr int KPAD = 256;
    constexpr int LSTR = KPAD + 8;
    constexpr int NROWS = 128;                 // N-half per block
    __shared__ u16 Bs[NROWS * LSTR];           // 67584 B -> 2 blocks/CU
    const int tid = threadIdx.x;
    const int wave = tid >> 6;
    const int lane = tid & 63;
    const int mrow = lane & 15;
    const int quad = lane >> 4;

    const int nch = (M + 127) >> 7;            // 128-row chunks
    const int cpx = (nch + 7) >> 3;
    const int bid = blockIdx.x;
    const int xcd = bid & 7;
    const int seq = bid >> 3;
    const long chunk = (long)xcd * cpx + (seq >> 1);
    if (chunk >= nch) return;                  // uniform pre-barrier exit
    const int nbase = (seq & 1) * NROWS;

    constexpr int KC = KPAD / 8;
    for (int i = tid; i < NROWS * KC; i += 512) {
        int r = i / KC, kc = i % KC;
        *(uint4*)&Bs[r * LSTR + kc * 8] = *(const uint4*)&Bt[(size_t)(nbase + r) * KPAD + kc * 8];
    }
    __syncthreads();

    const long mbase = chunk * 128 + wave * 16;
    long b = mbase + mrow;
    if (b >= M) b = M - 1;
    const int sa = b2a[b];
    unsigned joff[6];
    float jw[6];
#pragma unroll
    for (int j = 0; j < 6; ++j) {
        int r = a2b[sa * 6 + j];
        joff[j] = (unsigned)r * 512u + quad * 16u;   // byte offset into msg table
        jw[j] = w_bonds[r];
    }
    const unsigned roff = (unsigned)b2revb[b] * 512u + quad * 16u;
    const char* msgB = (const char*)msg;

    f32x4v acc[8];
#pragma unroll
    for (int j = 0; j < 8; ++j) acc[j] = (f32x4v){0.f, 0.f, 0.f, 0.f};

#pragma unroll 2
    for (int ke = 0; ke < KPAD; ke += 32) {
        const int kb = ke * 2;                 // byte offset within row
        uint4 vj[6];
#pragma unroll
        for (int j = 0; j < 6; ++j)
            vj[j] = *(const uint4*)(msgB + joff[j] + kb);
        uint4 vr = *(const uint4*)(msgB + roff + kb);

        // fp32 weighted sum of the 6 gathered rows
        float s[8] = {0.f, 0.f, 0.f, 0.f, 0.f, 0.f, 0.f, 0.f};
#pragma unroll
        for (int j = 0; j < 6; ++j) {
            unsigned p0 = vj[j].x, p1 = vj[j].y, p2 = vj[j].z, p3 = vj[j].w;
            if (RELUV) { p0 = relu2(p0); p1 = relu2(p1); p2 = relu2(p2); p3 = relu2(p3); }
            const float w = jw[j];
            s[0] += w * lo16(p0); s[1] += w * hi16(p0);
            s[2] += w * lo16(p1); s[3] += w * hi16(p1);
            s[4] += w * lo16(p2); s[5] += w * hi16(p2);
            s[6] += w * lo16(p3); s[7] += w * hi16(p3);
        }
        union { unsigned u[4]; bf16x8v v; } ua, ur;
        ua.u[0] = pack2(s[0], s[1]); ua.u[1] = pack2(s[2], s[3]);
        ua.u[2] = pack2(s[4], s[5]); ua.u[3] = pack2(s[6], s[7]);
        if (RELUV) {
            ur.u[0] = relu_neg2(vr.x); ur.u[1] = relu_neg2(vr.y);
            ur.u[2] = relu_neg2(vr.z); ur.u[3] = relu_neg2(vr.w);
        } else {
            ur.u[0] = neg2(vr.x); ur.u[1] = neg2(vr.y);
            ur.u[2] = neg2(vr.z); ur.u[3] = neg2(vr.w);
        }

#pragma unroll
        for (int j8 = 0; j8 < 8; ++j8) {
            bf16x8v b_frag = *(const bf16x8v*)&Bs[(j8 * 16 + mrow) * LSTR + ke + quad * 8];
            acc[j8] = __builtin_amdgcn_mfma_f32_16x16x32_bf16(ua.v, b_frag, acc[j8], 0, 0, 0);
            acc[j8] = __builtin_amdgcn_mfma_f32_16x16x32_bf16(ur.v, b_frag, acc[j8], 0, 0, 0);
        }
    }

    // epilogue: msg_new = relu(inp + acc)  (out0 may alias inp: own-idx read-then-write,
    // halves touch disjoint columns)
#pragma unroll
    for (int r = 0; r < 4; ++r) {
        long grow = mbase + quad * 4 + r;
        if (grow < M)
#pragma unroll
            for (int j8 = 0; j8 < 8; ++j8) {
                size_t idx = (size_t)grow * 256 + nbase + j8 * 16 + mrow;
                float s = bf2f(inp[idx]) + acc[j8][r];
                out0[idx] = f2bf(s > 0.f ? s : 0.f);
            }
    }
}

// ---------- readout GEMM: hid = relu([gather(msgB) | f_atoms] @ Wo^T + b) ----------
// The final per-atom gather (was gather16 + amsg buffer) is fused into the A-operand:
// per atom, 6 rows of msgB weighted-summed in fp32 -> bf16 frag. f_atoms fp32 fused.
// 128-col slices XCD-paired.
__global__ __launch_bounds__(512, 2)
void gemm_ro(const u16* __restrict__ msgT, const int* __restrict__ a2b,
             const float* __restrict__ w_bonds, const float* __restrict__ A2,
             const u16* __restrict__ Bt, int M,
             const float* __restrict__ bias, float* __restrict__ outf) {
    constexpr int KSPLIT = 256, K2 = 192, KMAX2 = 133, KPAD = 448;
    constexpr int LSTR = KPAD + 8;
    constexpr int NROWS = 128;
    __shared__ u16 Bs[NROWS * LSTR];
    const int tid = threadIdx.x;
    const int wave = tid >> 6;
    const int lane = tid & 63;
    const int mrow = lane & 15;
    const int quad = lane >> 4;

    const int nch = (M + 255) >> 8;
    const int cpx = (nch + 7) >> 3;
    const int bid = blockIdx.x;
    const int xcd = bid & 7;
    const int seq = bid >> 3;
    const long chunk = (long)xcd * cpx + (seq >> 1);
    if (chunk >= nch) return;
    const int nbase = (seq & 1) * NROWS;

    constexpr int KC = KPAD / 8;
    for (int i = tid; i < NROWS * KC; i += 512) {
        int r = i / KC, kc = i % KC;
        *(uint4*)&Bs[r * LSTR + kc * 8] =
            *(const uint4*)&Bt[(size_t)(nbase + r) * KPAD + kc * 8];
    }
    __syncthreads();

    const long mbase = chunk * 256 + wave * 32;
    long row[2];
    unsigned joff[2][6];
    float jw[2][6];
#pragma unroll
    for (int t = 0; t < 2; ++t) {
        long r = mbase + t * 16 + mrow;
        if (r >= M) r = M - 1;
        row[t] = r;
#pragma unroll
        for (int j = 0; j < 6; ++j) {
            int br = a2b[r * 6 + j];
            joff[t][j] = (unsigned)br * 512u + quad * 16u;
            jw[t][j] = w_bonds[br];
        }
    }
    const char* msgB = (const char*)msgT;

    f32x4v acc[2][8];
#pragma unroll
    for (int t = 0; t < 2; ++t)
#pragma unroll
        for (int j = 0; j < 8; ++j) acc[t][j] = (f32x4v){0.f, 0.f, 0.f, 0.f};

    // K-section 1: gathered a_message (on the fly, no relu - msgB already post-relu)
#pragma unroll 2
    for (int ke = 0; ke < KSPLIT; ke += 32) {
        const int kb = ke * 2;
        bf16x8v a_frag[2];
#pragma unroll
        for (int t = 0; t < 2; ++t) {
            uint4 vj[6];
#pragma unroll
            for (int j = 0; j < 6; ++j)
                vj[j] = *(const uint4*)(msgB + joff[t][j] + kb);
            float s[8] = {0.f, 0.f, 0.f, 0.f, 0.f, 0.f, 0.f, 0.f};
#pragma unroll
            for (int j = 0; j < 6; ++j) {
                const float w = jw[t][j];
                s[0] += w * lo16(vj[j].x); s[1] += w * hi16(vj[j].x);
                s[2] += w * lo16(vj[j].y); s[3] += w * hi16(vj[j].y);
                s[4] += w * lo16(vj[j].z); s[5] += w * hi16(vj[j].z);
                s[6] += w * lo16(vj[j].w); s[7] += w * hi16(vj[j].w);
            }
            union { unsigned u[4]; bf16x8v v; } ua;
            ua.u[0] = pack2(s[0], s[1]); ua.u[1] = pack2(s[2], s[3]);
            ua.u[2] = pack2(s[4], s[5]); ua.u[3] = pack2(s[6], s[7]);
            a_frag[t] = ua.v;
        }
#pragma unroll
        for (int j = 0; j < 8; ++j) {
            bf16x8v b_frag = *(const bf16x8v*)&Bs[(j * 16 + mrow) * LSTR + ke + quad * 8];
#pragma unroll
            for (int t = 0; t < 2; ++t)
                acc[t][j] = __builtin_amdgcn_mfma_f32_16x16x32_bf16(
                    a_frag[t], b_frag, acc[t][j], 0, 0, 0);
        }
    }
    // K-section 2: f_atoms (fp32 -> bf16 fused)
#pragma unroll 2
    for (int k0 = 0; k0 < K2; k0 += 32) {
        bf16x8v a_frag[2], b_frag[8];
#pragma unroll
        for (int t = 0; t < 2; ++t)
            a_frag[t] = load_cvt8(A2 + row[t] * KMAX2, k0 + quad * 8, KMAX2);
#pragma unroll
        for (int j = 0; j < 8; ++j)
            b_frag[j] = *(const bf16x8v*)&Bs[(j * 16 + mrow) * LSTR + KSPLIT + k0 + quad * 8];
#pragma unroll
        for (int t = 0; t < 2; ++t)
#pragma unroll
            for (int j = 0; j < 8; ++j)
                acc[t][j] = __builtin_amdgcn_mfma_f32_16x16x32_bf16(
                    a_frag[t], b_frag[j], acc[t][j], 0, 0, 0);
    }

#pragma unroll
    for (int t = 0; t < 2; ++t)
#pragma unroll
        for (int r = 0; r < 4; ++r) {
            long grow = mbase + t * 16 + quad * 4 + r;
            if (grow < M)
#pragma unroll
                for (int j = 0; j < 8; ++j) {
                    int gcol = nbase + j * 16 + mrow;
                    float s = acc[t][j][r] + bias[gcol];
                    outf[(size_t)grow * 256 + gcol] = s > 0.f ? s : 0.f;
                }
        }
}

// ---------- per-molecule weighted mean (mol_ids sorted) ----------
__global__ __launch_bounds__(256)
void aggregate_kernel(const float* __restrict__ hid, const float* __restrict__ w_atoms,
                      const int* __restrict__ mol_ids, const float* __restrict__ deg,
                      float* __restrict__ out, int nAtoms) {
    int m = blockIdx.x;
    int t = threadIdx.x;
    int lo = 0, hi = nAtoms;
    while (lo < hi) { int mid = (lo + hi) >> 1; if (mol_ids[mid] < m) lo = mid + 1; else hi = mid; }
    int start = lo;
    lo = start; hi = nAtoms;
    while (lo < hi) { int mid = (lo + hi) >> 1; if (mol_ids[mid] < m + 1) lo = mid + 1; else hi = mid; }
    int end = lo;
    float acc = 0.f, wsum = 0.f;
    for (int a = start; a < end; ++a) {
        float w = w_atoms[a];
        wsum += w;
        acc += w * hid[(size_t)a * 256 + t];
    }
    float res = (wsum > 0.f) ? deg[m] * acc / wsum : 0.f;
    out[m * 256 + t] = res;
}

// ---------- launch ----------
extern "C" void kernel_launch(void* const* d_in, const int* in_sizes, int n_in,
                              void* d_out, int out_size, void* d_ws, size_t ws_size,
                              hipStream_t stream) {
    const float* f_atoms = (const float*)d_in[0];
    const float* f_bonds = (const float*)d_in[1];
    const float* w_atoms = (const float*)d_in[2];
    const float* w_bonds = (const float*)d_in[3];
    const float* W_i     = (const float*)d_in[4];
    const float* W_h     = (const float*)d_in[5];
    const float* W_o     = (const float*)d_in[6];
    const float* b_o     = (const float*)d_in[7];
    const float* deg     = (const float*)d_in[8];
    const int*   a2b     = (const int*)d_in[9];
    const int*   b2a     = (const int*)d_in[10];
    const int*   b2revb  = (const int*)d_in[11];
    const int*   mol_ids = (const int*)d_in[12];
    float* out = (float*)d_out;

    const int nB = 250000, nA = 100000, nM = 2000;

    // ws layout (bytes):
    //  P0 @ 0     : inp bf16 [250k][256] = 128 MB (becomes msgB in-place after iter-1 GEMM)
    //  P1 @ 128M  : msgA bf16 [250k][256] = 128 MB
    //  P2 @ 256M  : hid fp32 [100k][256] = 102.4 MB
    //  P4 @ 435.2M: Wt_i (81,920) | Wt_h (131,072) | Wt_o (229,376)
    char* ws = (char*)d_ws;
    u16* inp    = (u16*)(ws);
    u16* msgA   = (u16*)(ws + 128000000L);
    float* hid  = (float*)(ws + 256000000L);
    u16* wt_i   = (u16*)(ws + 435200000L);
    u16* wt_h   = (u16*)(ws + 435200000L + 81920L);
    u16* wt_o   = (u16*)(ws + 435200000L + 81920L + 131072L);

    if (ws_size < 435642368UL) return;

    dim3 b256(256), b512(512);
    pack_w<<<dim3((256 * 160 + 255) / 256), b256, 0, stream>>>(W_i, wt_i, 147, 160);
    pack_w<<<dim3((256 * 256 + 255) / 256), b256, 0, stream>>>(W_h, wt_h, 256, 256);
    pack_wo<<<dim3((256 * 448 + 255) / 256), b256, 0, stream>>>(W_o, wt_o);

    // GEMM1: inp = f_bonds @ W_i^T (fp32 A, conversion fused)
    gemm_in<<<dim3(977), b512, 0, stream>>>(f_bonds, wt_i, nB, inp);

    // gemm_mp grid: 128-row chunks, 8 XCDs * cpx * 2 halves
    const int nchB = (nB + 127) >> 7, cpxB = (nchB + 7) >> 3;
    dim3 gmp(8 * cpxB * 2);
    // gemm_ro grid: 256-row chunks
    const int nchA = (nA + 255) >> 8, cpxA = (nchA + 7) >> 3;
    dim3 gro(8 * cpxA * 2);

    // iteration 0 (msg == relu(inp) on the fly everywhere)
    gemm_mp<true><<<gmp, b512, 0, stream>>>(
        inp, a2b, b2a, b2revb, w_bonds, wt_h, nB, inp, msgA);

    // iteration 1 (msgA already post-relu)
    gemm_mp<false><<<gmp, b512, 0, stream>>>(
        msgA, a2b, b2a, b2revb, w_bonds, wt_h, nB, inp, inp);   // msgB in-place over inp

    // final readout (gather fused into A-operand)
    gemm_ro<<<gro, b512, 0, stream>>>(inp /*msgB*/, a2b, w_bonds, f_atoms, wt_o, nA, b_o, hid);

    aggregate_kernel<<<dim3(nM), b256, 0, stream>>>(hid, w_atoms, mol_ids, deg, out, nA);
}

// Round 4
// 902.452 us; speedup vs baseline: 1.2204x; 1.2204x over previous
//
#include <hip/hip_runtime.h>
#include <hip/hip_bf16.h>

typedef unsigned short u16;
typedef __bf16 bf16x8v __attribute__((ext_vector_type(8)));
typedef float f32x4v __attribute__((ext_vector_type(4)));
typedef float f32x4u __attribute__((ext_vector_type(4))) __attribute__((aligned(4)));

// ---------- bf16 helpers (RNE) ----------
__device__ __forceinline__ float bf2f(u16 u) {
    union { float f; unsigned int i; } c; c.i = ((unsigned int)u) << 16; return c.f;
}
__device__ __forceinline__ u16 f2bf(float f) {
    union { float f; unsigned int i; } c; c.f = f;
    unsigned int i = c.i;
    unsigned int lsb = (i >> 16) & 1u;
    i += 0x7fffu + lsb;
    return (u16)(i >> 16);
}
__device__ __forceinline__ float lo16(unsigned u) { return bf2f((u16)(u & 0xffff)); }
__device__ __forceinline__ float hi16(unsigned u) { return bf2f((u16)(u >> 16)); }
__device__ __forceinline__ unsigned pack2(float lo, float hi) {
    return (unsigned)f2bf(lo) | ((unsigned)f2bf(hi) << 16);
}

// packed-bf16 bit tricks:
//   neg2:      x -> -x
//   relu_neg2: x -> -relu(x)
__device__ __forceinline__ unsigned neg2(unsigned u) { return u ^ 0x80008000u; }
__device__ __forceinline__ unsigned relu_neg2(unsigned u) {
    unsigned s = u & 0x80008000u;
    unsigned m = (s - (s >> 15)) | s;      // 0xffff per negative half
    return (u ^ 0x80008000u) & ~m;
}

// load 8 fp32 from rowp[k..k+7] (guarded, zero-padded), convert to bf16x8 fragment
__device__ __forceinline__ bf16x8v load_cvt8(const float* __restrict__ rowp, int k, int kmax) {
    union { unsigned u[4]; bf16x8v v; } r;
#pragma unroll
    for (int g = 0; g < 2; ++g) {
        int kk = k + g * 4;
        float f0, f1, f2, f3;
        if (kk + 3 < kmax) {
            f32x4u q = *(const f32x4u*)(rowp + kk);
            f0 = q.x; f1 = q.y; f2 = q.z; f3 = q.w;
        } else {
            f0 = (kk + 0 < kmax) ? rowp[kk + 0] : 0.f;
            f1 = (kk + 1 < kmax) ? rowp[kk + 1] : 0.f;
            f2 = (kk + 2 < kmax) ? rowp[kk + 2] : 0.f;
            f3 = (kk + 3 < kmax) ? rowp[kk + 3] : 0.f;
        }
        r.u[g * 2]     = pack2(f0, f1);
        r.u[g * 2 + 1] = pack2(f2, f3);
    }
    return r.v;
}

// ---------- all weight packing in ONE dispatch ----------
// ranges: [0,40960) Wt_i (K=147->160), [40960,106496) Wt_h (256), [106496,221184) Wt_o (448 reordered)
__global__ __launch_bounds__(256)
void pack_all(const float* __restrict__ W_i, const float* __restrict__ W_h,
              const float* __restrict__ W_o,
              u16* __restrict__ wti, u16* __restrict__ wth, u16* __restrict__ wto) {
    int idx = blockIdx.x * 256 + threadIdx.x;
    if (idx < 256 * 160) {
        int n = idx / 160, k = idx % 160;
        wti[idx] = f2bf(k < 147 ? W_i[k * 256 + n] : 0.f);
        return;
    }
    idx -= 256 * 160;
    if (idx < 256 * 256) {
        int n = idx / 256, k = idx % 256;
        wth[idx] = f2bf(W_h[k * 256 + n]);
        return;
    }
    idx -= 256 * 256;
    if (idx < 256 * 448) {
        int n = idx / 448, k = idx % 448;
        float v;
        if (k < 256)       v = W_o[(133 + k) * 256 + n];
        else if (k < 389)  v = W_o[(k - 256) * 256 + n];
        else               v = 0.f;
        wto[idx] = f2bf(v);
    }
}

// ---------- gather (2 atoms/thread, 12 independent 16B loads in flight) ----------
// amsg[a][h] = sum_j relu?(msg[a2b[a][j]][h]) * w_bonds[...]
template <bool RELU>
__global__ __launch_bounds__(256)
void gather16(const u16* __restrict__ msg, const int* __restrict__ a2b,
              const float* __restrict__ w_bonds, u16* __restrict__ out, int nAtoms) {
    int t = threadIdx.x;
    int g = t >> 5;                       // 0..7
    int co = (t & 31) * 8;
    int atom0 = blockIdx.x * 16 + g;      // grid = nAtoms/16 (exact)
    int atom1 = atom0 + 8;
    if (atom1 >= nAtoms) { if (atom0 >= nAtoms) return; atom1 = atom0; }

    int bidx[12];
#pragma unroll
    for (int j = 0; j < 6; ++j) {
        bidx[j]     = a2b[atom0 * 6 + j];
        bidx[6 + j] = a2b[atom1 * 6 + j];
    }
    float w[12];
#pragma unroll
    for (int j = 0; j < 12; ++j) w[j] = w_bonds[bidx[j]];
    uint4 v[12];
#pragma unroll
    for (int j = 0; j < 12; ++j)
        v[j] = *(const uint4*)(msg + (size_t)bidx[j] * 256 + co);

    float a0[8] = {0,0,0,0,0,0,0,0}, a1[8] = {0,0,0,0,0,0,0,0};
#pragma unroll
    for (int j = 0; j < 6; ++j) {
        unsigned p[4] = {v[j].x, v[j].y, v[j].z, v[j].w};
        unsigned q[4] = {v[6+j].x, v[6+j].y, v[6+j].z, v[6+j].w};
#pragma unroll
        for (int c = 0; c < 4; ++c) {
            float m0 = lo16(p[c]), m1 = hi16(p[c]);
            float n0 = lo16(q[c]), n1 = hi16(q[c]);
            if (RELU) {
                m0 = fmaxf(m0, 0.f); m1 = fmaxf(m1, 0.f);
                n0 = fmaxf(n0, 0.f); n1 = fmaxf(n1, 0.f);
            }
            a0[c * 2]     += w[j] * m0;
            a0[c * 2 + 1] += w[j] * m1;
            a1[c * 2]     += w[6+j] * n0;
            a1[c * 2 + 1] += w[6+j] * n1;
        }
    }
    uint4 o0, o1;
    o0.x = pack2(a0[0], a0[1]); o0.y = pack2(a0[2], a0[3]);
    o0.z = pack2(a0[4], a0[5]); o0.w = pack2(a0[6], a0[7]);
    o1.x = pack2(a1[0], a1[1]); o1.y = pack2(a1[2], a1[3]);
    o1.z = pack2(a1[4], a1[5]); o1.w = pack2(a1[6], a1[7]);
    *(uint4*)(out + (size_t)atom0 * 256 + co) = o0;
    if (atom1 != atom0)
        *(uint4*)(out + (size_t)atom1 * 256 + co) = o1;
}

// ---------- GEMM1: inp = f_bonds(fp32, stride 147) @ W_i^T, conversion fused into A-load ----------
__global__ __launch_bounds__(512, 2)
void gemm_in(const float* __restrict__ A, const u16* __restrict__ Bt, int M,
             u16* __restrict__ out0) {
    constexpr int KPAD = 160, KMAX = 147, ASTR = 147;
    constexpr int LSTR = KPAD + 8;
    __shared__ u16 Bs[256 * LSTR];
    const int tid = threadIdx.x;
    const int wave = tid >> 6;
    const int lane = tid & 63;
    const int mrow = lane & 15;
    const int quad = lane >> 4;

    constexpr int KC = KPAD / 8;
    for (int i = tid; i < 256 * KC; i += 512) {
        int r = i / KC, kc = i % KC;
        *(uint4*)&Bs[r * LSTR + kc * 8] = *(const uint4*)&Bt[(size_t)r * KPAD + kc * 8];
    }
    __syncthreads();

    for (long chunk = blockIdx.x; chunk * 256 < (long)M; chunk += gridDim.x) {
        const long mbase = chunk * 256 + wave * 32;
        const float* rowp[2];
#pragma unroll
        for (int t = 0; t < 2; ++t) {
            long r = mbase + t * 16 + mrow;
            if (r >= M) r = M - 1;
            rowp[t] = A + r * ASTR;
        }

        f32x4v acc[2][16];
#pragma unroll
        for (int t = 0; t < 2; ++t)
#pragma unroll
            for (int j = 0; j < 16; ++j) acc[t][j] = (f32x4v){0.f, 0.f, 0.f, 0.f};

#pragma unroll 2
        for (int k0 = 0; k0 < KPAD; k0 += 32) {
            bf16x8v a_frag[2];
#pragma unroll
            for (int t = 0; t < 2; ++t)
                a_frag[t] = load_cvt8(rowp[t], k0 + quad * 8, KMAX);
#pragma unroll
            for (int jg = 0; jg < 4; ++jg) {
                bf16x8v b_frag[4];
#pragma unroll
                for (int j4 = 0; j4 < 4; ++j4)
                    b_frag[j4] = *(const bf16x8v*)&Bs[((jg * 4 + j4) * 16 + mrow) * LSTR + k0 + quad * 8];
#pragma unroll
                for (int t = 0; t < 2; ++t)
#pragma unroll
                    for (int j4 = 0; j4 < 4; ++j4)
                        acc[t][jg * 4 + j4] = __builtin_amdgcn_mfma_f32_16x16x32_bf16(
                            a_frag[t], b_frag[j4], acc[t][jg * 4 + j4], 0, 0, 0);
            }
        }

#pragma unroll
        for (int t = 0; t < 2; ++t)
#pragma unroll
            for (int r = 0; r < 4; ++r) {
                long grow = mbase + t * 16 + quad * 4 + r;
                if (grow < M)
#pragma unroll
                    for (int j = 0; j < 16; ++j)
                        out0[(size_t)grow * 256 + j * 16 + mrow] = f2bf(acc[t][j][r]);
            }
    }
}

// ---------- fused message-passing GEMM (round-2 structure + 2-deep gather pipeline) ----------
// msg_new[b][:] = relu( inp[b] + (amsg[b2a[b]] - relu?(msgsrc[b2revb[b]])) @ Wh^T )
// (a - relu(r)) @ W = a @ W + (-relu(r)) @ W  -> dual MFMA, A raw bf16.
// XCD-paired N-halves (proven: dedups the duplicate half's gather via XCD-L2).
// New: k-loop fully unrolled with 2-deep register double-buffer on the gathered
// loads -> 8 independent 16B loads in flight per lane (was 4): latency hiding.
template <bool RELUV>
__global__ __launch_bounds__(512, 4)
void gemm_mp(const u16* __restrict__ amsg, const u16* __restrict__ msgsrc,
             const int* __restrict__ b2a, const int* __restrict__ b2revb,
             const u16* __restrict__ Bt, int M,
             const u16* __restrict__ inp, u16* __restrict__ out0) {
    constexpr int KPAD = 256;
    constexpr int LSTR = KPAD + 8;
    constexpr int NROWS = 128;                 // N-half per block
    __shared__ u16 Bs[NROWS * LSTR];           // 67584 B -> 2 blocks/CU
    const int tid = threadIdx.x;
    const int wave = tid >> 6;
    const int lane = tid & 63;
    const int mrow = lane & 15;
    const int quad = lane >> 4;

    const int nch = (M + 255) >> 8;
    const int cpx = (nch + 7) >> 3;            // chunks per XCD
    const int bid = blockIdx.x;
    const int xcd = bid & 7;
    const int seq = bid >> 3;
    const long chunk = (long)xcd * cpx + (seq >> 1);
    if (chunk >= nch) return;                  // uniform pre-barrier exit
    const int nbase = (seq & 1) * NROWS;

    constexpr int KC = KPAD / 8;
    for (int i = tid; i < NROWS * KC; i += 512) {
        int r = i / KC, kc = i % KC;
        *(uint4*)&Bs[r * LSTR + kc * 8] = *(const uint4*)&Bt[(size_t)(nbase + r) * KPAD + kc * 8];
    }
    __syncthreads();

    const long mbase = chunk * 256 + wave * 32;
    size_t soff[2], roff[2];
#pragma unroll
    for (int t = 0; t < 2; ++t) {
        long b = mbase + t * 16 + mrow;
        if (b >= M) b = M - 1;
        soff[t] = (size_t)b2a[b] * 256 + quad * 8;
        roff[t] = (size_t)b2revb[b] * 256 + quad * 8;
    }

    f32x4v acc[2][8];
#pragma unroll
    for (int t = 0; t < 2; ++t)
#pragma unroll
        for (int j = 0; j < 8; ++j) acc[t][j] = (f32x4v){0.f, 0.f, 0.f, 0.f};

    // 2-deep register pipeline over 8 k-chunks (fully unrolled: static buffer idx)
    uint4 va[2][2], vr[2][2];
#pragma unroll
    for (int t = 0; t < 2; ++t) {
        va[0][t] = *(const uint4*)&amsg[soff[t]];
        vr[0][t] = *(const uint4*)&msgsrc[roff[t]];
    }
#pragma unroll
    for (int kk = 0; kk < 8; ++kk) {
        const int k0 = kk * 32;
        const int cur = kk & 1, nxt = cur ^ 1;
        if (kk < 7) {
#pragma unroll
            for (int t = 0; t < 2; ++t) {
                va[nxt][t] = *(const uint4*)&amsg[soff[t] + k0 + 32];
                vr[nxt][t] = *(const uint4*)&msgsrc[roff[t] + k0 + 32];
            }
        }
        bf16x8v a1[2], a2[2];
#pragma unroll
        for (int t = 0; t < 2; ++t) {
            union { uint4 q; bf16x8v v; } ua, ur;
            ua.q = va[cur][t];
            uint4 w = vr[cur][t];
            if (RELUV) {
                ur.q.x = relu_neg2(w.x); ur.q.y = relu_neg2(w.y);
                ur.q.z = relu_neg2(w.z); ur.q.w = relu_neg2(w.w);
            } else {
                ur.q.x = neg2(w.x); ur.q.y = neg2(w.y);
                ur.q.z = neg2(w.z); ur.q.w = neg2(w.w);
            }
            a1[t] = ua.v;
            a2[t] = ur.v;
        }
#pragma unroll
        for (int jg = 0; jg < 2; ++jg) {
            bf16x8v b_frag[4];
#pragma unroll
            for (int j4 = 0; j4 < 4; ++j4)
                b_frag[j4] = *(const bf16x8v*)&Bs[((jg * 4 + j4) * 16 + mrow) * LSTR + k0 + quad * 8];
#pragma unroll
            for (int t = 0; t < 2; ++t)
#pragma unroll
                for (int j4 = 0; j4 < 4; ++j4) {
                    acc[t][jg * 4 + j4] = __builtin_amdgcn_mfma_f32_16x16x32_bf16(
                        a1[t], b_frag[j4], acc[t][jg * 4 + j4], 0, 0, 0);
                    acc[t][jg * 4 + j4] = __builtin_amdgcn_mfma_f32_16x16x32_bf16(
                        a2[t], b_frag[j4], acc[t][jg * 4 + j4], 0, 0, 0);
                }
        }
    }

    // epilogue: msg_new = relu(inp + acc)   (out0 may alias inp: own-idx read-then-write,
    // halves touch disjoint columns)
#pragma unroll
    for (int t = 0; t < 2; ++t)
#pragma unroll
        for (int r = 0; r < 4; ++r) {
            long grow = mbase + t * 16 + quad * 4 + r;
            if (grow < M)
#pragma unroll
                for (int j = 0; j < 8; ++j) {
                    size_t idx = (size_t)grow * 256 + nbase + j * 16 + mrow;
                    float s = bf2f(inp[idx]) + acc[t][j][r];
                    out0[idx] = f2bf(s > 0.f ? s : 0.f);
                }
        }
}

// ---------- readout GEMM: hid = relu([amsg | f_atoms] @ Wo^T + b), f_atoms fp32 fused ----------
// 128-col slices XCD-paired (A reads duplicated across halves -> share via L2).
__global__ __launch_bounds__(512, 2)
void gemm_ro(const u16* __restrict__ A1, const float* __restrict__ A2,
             const u16* __restrict__ Bt, int M,
             const float* __restrict__ bias, float* __restrict__ outf) {
    constexpr int KPAD = 448, KSPLIT = 256, K2 = 192, KMAX2 = 133;
    constexpr int LSTR = KPAD + 8;
    constexpr int NROWS = 128;
    __shared__ u16 Bs[NROWS * LSTR];
    const int tid = threadIdx.x;
    const int wave = tid >> 6;
    const int lane = tid & 63;
    const int mrow = lane & 15;
    const int quad = lane >> 4;

    const int nch = (M + 255) >> 8;
    const int cpx = (nch + 7) >> 3;
    const int bid = blockIdx.x;
    const int xcd = bid & 7;
    const int seq = bid >> 3;
    const long chunk = (long)xcd * cpx + (seq >> 1);
    if (chunk >= nch) return;
    const int nbase = (seq & 1) * NROWS;

    constexpr int KC = KPAD / 8;
    for (int i = tid; i < NROWS * KC; i += 512) {
        int r = i / KC, kc = i % KC;
        *(uint4*)&Bs[r * LSTR + kc * 8] =
            *(const uint4*)&Bt[(size_t)(nbase + r) * KPAD + kc * 8];
    }
    __syncthreads();

    const long mbase = chunk * 256 + wave * 32;
    long row[2];
#pragma unroll
    for (int t = 0; t < 2; ++t) {
        long r = mbase + t * 16 + mrow;
        if (r >= M) r = M - 1;
        row[t] = r;
    }

    f32x4v acc[2][8];
#pragma unroll
    for (int t = 0; t < 2; ++t)
#pragma unroll
        for (int j = 0; j < 8; ++j) acc[t][j] = (f32x4v){0.f, 0.f, 0.f, 0.f};

#pragma unroll 2
    for (int k0 = 0; k0 < KSPLIT; k0 += 32) {
        bf16x8v a_frag[2], b_frag[8];
#pragma unroll
        for (int t = 0; t < 2; ++t)
            a_frag[t] = *(const bf16x8v*)&A1[row[t] * KSPLIT + k0 + quad * 8];
#pragma unroll
        for (int j = 0; j < 8; ++j)
            b_frag[j] = *(const bf16x8v*)&Bs[(j * 16 + mrow) * LSTR + k0 + quad * 8];
#pragma unroll
        for (int t = 0; t < 2; ++t)
#pragma unroll
            for (int j = 0; j < 8; ++j)
                acc[t][j] = __builtin_amdgcn_mfma_f32_16x16x32_bf16(
                    a_frag[t], b_frag[j], acc[t][j], 0, 0, 0);
    }
#pragma unroll 2
    for (int k0 = 0; k0 < K2; k0 += 32) {
        bf16x8v a_frag[2], b_frag[8];
#pragma unroll
        for (int t = 0; t < 2; ++t)
            a_frag[t] = load_cvt8(A2 + row[t] * KMAX2, k0 + quad * 8, KMAX2);
#pragma unroll
        for (int j = 0; j < 8; ++j)
            b_frag[j] = *(const bf16x8v*)&Bs[(j * 16 + mrow) * LSTR + KSPLIT + k0 + quad * 8];
#pragma unroll
        for (int t = 0; t < 2; ++t)
#pragma unroll
            for (int j = 0; j < 8; ++j)
                acc[t][j] = __builtin_amdgcn_mfma_f32_16x16x32_bf16(
                    a_frag[t], b_frag[j], acc[t][j], 0, 0, 0);
    }

#pragma unroll
    for (int t = 0; t < 2; ++t)
#pragma unroll
        for (int r = 0; r < 4; ++r) {
            long grow = mbase + t * 16 + quad * 4 + r;
            if (grow < M)
#pragma unroll
                for (int j = 0; j < 8; ++j) {
                    int gcol = nbase + j * 16 + mrow;
                    float s = acc[t][j][r] + bias[gcol];
                    outf[(size_t)grow * 256 + gcol] = s > 0.f ? s : 0.f;
                }
        }
}

// ---------- per-molecule weighted mean (mol_ids sorted) ----------
__global__ __launch_bounds__(256)
void aggregate_kernel(const float* __restrict__ hid, const float* __restrict__ w_atoms,
                      const int* __restrict__ mol_ids, const float* __restrict__ deg,
                      float* __restrict__ out, int nAtoms) {
    int m = blockIdx.x;
    int t = threadIdx.x;
    int lo = 0, hi = nAtoms;
    while (lo < hi) { int mid = (lo + hi) >> 1; if (mol_ids[mid] < m) lo = mid + 1; else hi = mid; }
    int start = lo;
    lo = start; hi = nAtoms;
    while (lo < hi) { int mid = (lo + hi) >> 1; if (mol_ids[mid] < m + 1) lo = mid + 1; else hi = mid; }
    int end = lo;
    float acc = 0.f, wsum = 0.f;
    for (int a = start; a < end; ++a) {
        float w = w_atoms[a];
        wsum += w;
        acc += w * hid[(size_t)a * 256 + t];
    }
    float res = (wsum > 0.f) ? deg[m] * acc / wsum : 0.f;
    out[m * 256 + t] = res;
}

// ---------- launch ----------
extern "C" void kernel_launch(void* const* d_in, const int* in_sizes, int n_in,
                              void* d_out, int out_size, void* d_ws, size_t ws_size,
                              hipStream_t stream) {
    const float* f_atoms = (const float*)d_in[0];
    const float* f_bonds = (const float*)d_in[1];
    const float* w_atoms = (const float*)d_in[2];
    const float* w_bonds = (const float*)d_in[3];
    const float* W_i     = (const float*)d_in[4];
    const float* W_h     = (const float*)d_in[5];
    const float* W_o     = (const float*)d_in[6];
    const float* b_o     = (const float*)d_in[7];
    const float* deg     = (const float*)d_in[8];
    const int*   a2b     = (const int*)d_in[9];
    const int*   b2a     = (const int*)d_in[10];
    const int*   b2revb  = (const int*)d_in[11];
    const int*   mol_ids = (const int*)d_in[12];
    float* out = (float*)d_out;

    const int nB = 250000, nA = 100000, nM = 2000;

    // ws layout (bytes):
    //  P0 @ 0     : inp bf16 [250k][256] = 128 MB (becomes msgB in-place after iter-1 GEMM)
    //  P1 @ 128M  : msgA bf16 [250k][256] = 128 MB
    //  P2 @ 256M  : hid fp32 [100k][256] = 102.4 MB
    //  P3 @ 384M  : amsg bf16 [100k][256] = 51.2 MB
    //  P4 @ 435.2M: Wt_i (81,920) | Wt_h (131,072) | Wt_o (229,376)
    char* ws = (char*)d_ws;
    u16* inp    = (u16*)(ws);
    u16* msgA   = (u16*)(ws + 128000000L);
    float* hid  = (float*)(ws + 256000000L);
    u16* amsg   = (u16*)(ws + 384000000L);
    u16* wt_i   = (u16*)(ws + 435200000L);
    u16* wt_h   = (u16*)(ws + 435200000L + 81920L);
    u16* wt_o   = (u16*)(ws + 435200000L + 81920L + 131072L);

    if (ws_size < 435642368UL) return;

    dim3 b256(256), b512(512);
    pack_all<<<dim3((256 * 160 + 256 * 256 + 256 * 448 + 255) / 256), b256, 0, stream>>>(
        W_i, W_h, W_o, wt_i, wt_h, wt_o);

    // GEMM1: inp = f_bonds @ W_i^T (fp32 A, conversion fused)
    gemm_in<<<dim3(977), b512, 0, stream>>>(f_bonds, wt_i, nB, inp);

    // gemm_mp grid: 8 XCDs * cpx * 2 halves
    const int nchB = (nB + 255) >> 8, cpxB = (nchB + 7) >> 3;
    dim3 gmp(8 * cpxB * 2);
    const int nchA = (nA + 255) >> 8, cpxA = (nchA + 7) >> 3;
    dim3 gro(8 * cpxA * 2);

    // iteration 0 (msg == relu(inp) on the fly everywhere)
    gather16<true><<<dim3((nA + 15) / 16), b256, 0, stream>>>(inp, a2b, w_bonds, amsg, nA);
    gemm_mp<true><<<gmp, b512, 0, stream>>>(
        amsg, inp, b2a, b2revb, wt_h, nB, inp, msgA);

    // iteration 1
    gather16<false><<<dim3((nA + 15) / 16), b256, 0, stream>>>(msgA, a2b, w_bonds, amsg, nA);
    gemm_mp<false><<<gmp, b512, 0, stream>>>(
        amsg, msgA, b2a, b2revb, wt_h, nB, inp, inp);   // msgB in-place over inp

    // final readout
    gather16<false><<<dim3((nA + 15) / 16), b256, 0, stream>>>(inp /*msgB*/, a2b, w_bonds, amsg, nA);
    gemm_ro<<<gro, b512, 0, stream>>>(amsg, f_atoms, wt_o, nA, b_o, hid);

    aggregate_kernel<<<dim3(nM), b256, 0, stream>>>(hid, w_atoms, mol_ids, deg, out, nA);
}

// Round 5
// 857.755 us; speedup vs baseline: 1.2839x; 1.0521x over previous
//
#include <hip/hip_runtime.h>
#include <hip/hip_bf16.h>

typedef unsigned short u16;
typedef __bf16 bf16x8v __attribute__((ext_vector_type(8)));
typedef float f32x4v __attribute__((ext_vector_type(4)));
typedef float f32x4u __attribute__((ext_vector_type(4))) __attribute__((aligned(4)));

// ---------- bf16 helpers (RNE) ----------
__device__ __forceinline__ float bf2f(u16 u) {
    union { float f; unsigned int i; } c; c.i = ((unsigned int)u) << 16; return c.f;
}
__device__ __forceinline__ u16 f2bf(float f) {
    union { float f; unsigned int i; } c; c.f = f;
    unsigned int i = c.i;
    unsigned int lsb = (i >> 16) & 1u;
    i += 0x7fffu + lsb;
    return (u16)(i >> 16);
}
__device__ __forceinline__ float lo16(unsigned u) { return bf2f((u16)(u & 0xffff)); }
__device__ __forceinline__ float hi16(unsigned u) { return bf2f((u16)(u >> 16)); }
__device__ __forceinline__ unsigned pack2(float lo, float hi) {
    return (unsigned)f2bf(lo) | ((unsigned)f2bf(hi) << 16);
}

// packed-bf16 bit tricks:
//   neg2:      x -> -x
//   relu_neg2: x -> -relu(x)
__device__ __forceinline__ unsigned neg2(unsigned u) { return u ^ 0x80008000u; }
__device__ __forceinline__ unsigned relu_neg2(unsigned u) {
    unsigned s = u & 0x80008000u;
    unsigned m = (s - (s >> 15)) | s;      // 0xffff per negative half
    return (u ^ 0x80008000u) & ~m;
}

// load 8 fp32 from rowp[k..k+7] (guarded, zero-padded), convert to bf16x8 fragment
__device__ __forceinline__ bf16x8v load_cvt8(const float* __restrict__ rowp, int k, int kmax) {
    union { unsigned u[4]; bf16x8v v; } r;
#pragma unroll
    for (int g = 0; g < 2; ++g) {
        int kk = k + g * 4;
        float f0, f1, f2, f3;
        if (kk + 3 < kmax) {
            f32x4u q = *(const f32x4u*)(rowp + kk);
            f0 = q.x; f1 = q.y; f2 = q.z; f3 = q.w;
        } else {
            f0 = (kk + 0 < kmax) ? rowp[kk + 0] : 0.f;
            f1 = (kk + 1 < kmax) ? rowp[kk + 1] : 0.f;
            f2 = (kk + 2 < kmax) ? rowp[kk + 2] : 0.f;
            f3 = (kk + 3 < kmax) ? rowp[kk + 3] : 0.f;
        }
        r.u[g * 2]     = pack2(f0, f1);
        r.u[g * 2 + 1] = pack2(f2, f3);
    }
    return r.v;
}

// ---------- all weight packing in ONE dispatch ----------
__global__ __launch_bounds__(256)
void pack_all(const float* __restrict__ W_i, const float* __restrict__ W_h,
              const float* __restrict__ W_o,
              u16* __restrict__ wti, u16* __restrict__ wth, u16* __restrict__ wto) {
    int idx = blockIdx.x * 256 + threadIdx.x;
    if (idx < 256 * 160) {
        int n = idx / 160, k = idx % 160;
        wti[idx] = f2bf(k < 147 ? W_i[k * 256 + n] : 0.f);
        return;
    }
    idx -= 256 * 160;
    if (idx < 256 * 256) {
        int n = idx / 256, k = idx % 256;
        wth[idx] = f2bf(W_h[k * 256 + n]);
        return;
    }
    idx -= 256 * 256;
    if (idx < 256 * 448) {
        int n = idx / 448, k = idx % 448;
        float v;
        if (k < 256)       v = W_o[(133 + k) * 256 + n];
        else if (k < 389)  v = W_o[(k - 256) * 256 + n];
        else               v = 0.f;
        wto[idx] = f2bf(v);
    }
}

// ---------- gather (2 atoms/thread, 12 independent 16B loads in flight) ----------
template <bool RELU>
__global__ __launch_bounds__(256)
void gather16(const u16* __restrict__ msg, const int* __restrict__ a2b,
              const float* __restrict__ w_bonds, u16* __restrict__ out, int nAtoms) {
    int t = threadIdx.x;
    int g = t >> 5;                       // 0..7
    int co = (t & 31) * 8;
    int atom0 = blockIdx.x * 16 + g;
    int atom1 = atom0 + 8;
    if (atom1 >= nAtoms) { if (atom0 >= nAtoms) return; atom1 = atom0; }

    int bidx[12];
#pragma unroll
    for (int j = 0; j < 6; ++j) {
        bidx[j]     = a2b[atom0 * 6 + j];
        bidx[6 + j] = a2b[atom1 * 6 + j];
    }
    float w[12];
#pragma unroll
    for (int j = 0; j < 12; ++j) w[j] = w_bonds[bidx[j]];
    uint4 v[12];
#pragma unroll
    for (int j = 0; j < 12; ++j)
        v[j] = *(const uint4*)(msg + (size_t)bidx[j] * 256 + co);

    float a0[8] = {0,0,0,0,0,0,0,0}, a1[8] = {0,0,0,0,0,0,0,0};
#pragma unroll
    for (int j = 0; j < 6; ++j) {
        unsigned p[4] = {v[j].x, v[j].y, v[j].z, v[j].w};
        unsigned q[4] = {v[6+j].x, v[6+j].y, v[6+j].z, v[6+j].w};
#pragma unroll
        for (int c = 0; c < 4; ++c) {
            float m0 = lo16(p[c]), m1 = hi16(p[c]);
            float n0 = lo16(q[c]), n1 = hi16(q[c]);
            if (RELU) {
                m0 = fmaxf(m0, 0.f); m1 = fmaxf(m1, 0.f);
                n0 = fmaxf(n0, 0.f); n1 = fmaxf(n1, 0.f);
            }
            a0[c * 2]     += w[j] * m0;
            a0[c * 2 + 1] += w[j] * m1;
            a1[c * 2]     += w[6+j] * n0;
            a1[c * 2 + 1] += w[6+j] * n1;
        }
    }
    uint4 o0, o1;
    o0.x = pack2(a0[0], a0[1]); o0.y = pack2(a0[2], a0[3]);
    o0.z = pack2(a0[4], a0[5]); o0.w = pack2(a0[6], a0[7]);
    o1.x = pack2(a1[0], a1[1]); o1.y = pack2(a1[2], a1[3]);
    o1.z = pack2(a1[4], a1[5]); o1.w = pack2(a1[6], a1[7]);
    *(uint4*)(out + (size_t)atom0 * 256 + co) = o0;
    if (atom1 != atom0)
        *(uint4*)(out + (size_t)atom1 * 256 + co) = o1;
}

// ---------- GEMM1: inp = f_bonds(fp32, stride 147) @ W_i^T, conversion fused into A-load ----------
__global__ __launch_bounds__(512, 2)
void gemm_in(const float* __restrict__ A, const u16* __restrict__ Bt, int M,
             u16* __restrict__ out0) {
    constexpr int KPAD = 160, KMAX = 147, ASTR = 147;
    constexpr int LSTR = KPAD + 8;
    __shared__ u16 Bs[256 * LSTR];
    const int tid = threadIdx.x;
    const int wave = tid >> 6;
    const int lane = tid & 63;
    const int mrow = lane & 15;
    const int quad = lane >> 4;

    constexpr int KC = KPAD / 8;
    for (int i = tid; i < 256 * KC; i += 512) {
        int r = i / KC, kc = i % KC;
        *(uint4*)&Bs[r * LSTR + kc * 8] = *(const uint4*)&Bt[(size_t)r * KPAD + kc * 8];
    }
    __syncthreads();

    for (long chunk = blockIdx.x; chunk * 256 < (long)M; chunk += gridDim.x) {
        const long mbase = chunk * 256 + wave * 32;
        const float* rowp[2];
#pragma unroll
        for (int t = 0; t < 2; ++t) {
            long r = mbase + t * 16 + mrow;
            if (r >= M) r = M - 1;
            rowp[t] = A + r * ASTR;
        }

        f32x4v acc[2][16];
#pragma unroll
        for (int t = 0; t < 2; ++t)
#pragma unroll
            for (int j = 0; j < 16; ++j) acc[t][j] = (f32x4v){0.f, 0.f, 0.f, 0.f};

#pragma unroll 2
        for (int k0 = 0; k0 < KPAD; k0 += 32) {
            bf16x8v a_frag[2];
#pragma unroll
            for (int t = 0; t < 2; ++t)
                a_frag[t] = load_cvt8(rowp[t], k0 + quad * 8, KMAX);
#pragma unroll
            for (int jg = 0; jg < 4; ++jg) {
                bf16x8v b_frag[4];
#pragma unroll
                for (int j4 = 0; j4 < 4; ++j4)
                    b_frag[j4] = *(const bf16x8v*)&Bs[((jg * 4 + j4) * 16 + mrow) * LSTR + k0 + quad * 8];
#pragma unroll
                for (int t = 0; t < 2; ++t)
#pragma unroll
                    for (int j4 = 0; j4 < 4; ++j4)
                        acc[t][jg * 4 + j4] = __builtin_amdgcn_mfma_f32_16x16x32_bf16(
                            a_frag[t], b_frag[j4], acc[t][jg * 4 + j4], 0, 0, 0);
            }
        }

#pragma unroll
        for (int t = 0; t < 2; ++t)
#pragma unroll
            for (int r = 0; r < 4; ++r) {
                long grow = mbase + t * 16 + quad * 4 + r;
                if (grow < M)
#pragma unroll
                    for (int j = 0; j < 16; ++j)
                        out0[(size_t)grow * 256 + j * 16 + mrow] = f2bf(acc[t][j][r]);
            }
    }
}

// ---------- fused message-passing GEMM (1024 thr, full-N, 16 waves/CU) ----------
// msg_new[b][:] = relu( inp[b] + (amsg[b2a[b]] - relu?(msgsrc[b2revb[b]])) @ Wh^T )
// (a - relu(r)) @ W = a @ W + (-relu(r)) @ W  -> dual MFMA, A raw bf16.
// One block = 128 bond rows x full 256 cols. 16 waves; wave = 16 rows x 128 cols
// (wgrp = wave>>1 row group, chalf = wave&1 col half). acc[8] = 32 VGPR -> <=128.
// LDS = full 256-col weight (135 KB) -> 1 block/CU but 16 waves/CU = 50% occ.
// Each gathered row fetched ONCE per block (col-half waves share via same-CU L1/L2);
// output rows written as full 512B lines by one block (write-combining guaranteed).
template <bool RELUV>
__global__ __launch_bounds__(1024, 4)
void gemm_mp(const u16* __restrict__ amsg, const u16* __restrict__ msgsrc,
             const int* __restrict__ b2a, const int* __restrict__ b2revb,
             const u16* __restrict__ Bt, int M,
             const u16* __restrict__ inp, u16* __restrict__ out0) {
    constexpr int KPAD = 256;
    constexpr int LSTR = KPAD + 8;
    __shared__ u16 Bs[256 * LSTR];             // 135168 B
    const int tid = threadIdx.x;
    const int wave = tid >> 6;                 // 0..15
    const int lane = tid & 63;
    const int mrow = lane & 15;
    const int quad = lane >> 4;
    const int wgrp = wave >> 1;                // 0..7 row group
    const int nbase = (wave & 1) * 128;        // col half

    for (int i = tid; i < 256 * 32; i += 1024) {
        int r = i >> 5, kc = i & 31;
        *(uint4*)&Bs[r * LSTR + kc * 8] = *(const uint4*)&Bt[(size_t)r * KPAD + kc * 8];
    }
    __syncthreads();

    const long mbase = (long)blockIdx.x * 128 + wgrp * 16;
    long b = mbase + mrow;
    if (b >= M) b = M - 1;
    const size_t soff = (size_t)b2a[b] * 256 + quad * 8;
    const size_t roff = (size_t)b2revb[b] * 256 + quad * 8;

    f32x4v acc[8];
#pragma unroll
    for (int j = 0; j < 8; ++j) acc[j] = (f32x4v){0.f, 0.f, 0.f, 0.f};

#pragma unroll 2
    for (int k0 = 0; k0 < KPAD; k0 += 32) {
        uint4 va = *(const uint4*)&amsg[soff + k0];
        uint4 vr = *(const uint4*)&msgsrc[roff + k0];
        union { uint4 q; bf16x8v v; } ua, ur;
        ua.q = va;
        if (RELUV) {
            ur.q.x = relu_neg2(vr.x); ur.q.y = relu_neg2(vr.y);
            ur.q.z = relu_neg2(vr.z); ur.q.w = relu_neg2(vr.w);
        } else {
            ur.q.x = neg2(vr.x); ur.q.y = neg2(vr.y);
            ur.q.z = neg2(vr.z); ur.q.w = neg2(vr.w);
        }
#pragma unroll
        for (int j = 0; j < 8; ++j) {
            bf16x8v b_frag = *(const bf16x8v*)&Bs[(nbase + j * 16 + mrow) * LSTR + k0 + quad * 8];
            acc[j] = __builtin_amdgcn_mfma_f32_16x16x32_bf16(ua.v, b_frag, acc[j], 0, 0, 0);
            acc[j] = __builtin_amdgcn_mfma_f32_16x16x32_bf16(ur.v, b_frag, acc[j], 0, 0, 0);
        }
    }

    // epilogue: msg_new = relu(inp + acc)  (out0 may alias inp: own-idx read-then-write)
#pragma unroll
    for (int r = 0; r < 4; ++r) {
        long grow = mbase + quad * 4 + r;
        if (grow < M)
#pragma unroll
            for (int j = 0; j < 8; ++j) {
                size_t idx = (size_t)grow * 256 + nbase + j * 16 + mrow;
                float s = bf2f(inp[idx]) + acc[j][r];
                out0[idx] = f2bf(s > 0.f ? s : 0.f);
            }
    }
}

// ---------- readout GEMM: hid = relu([amsg | f_atoms] @ Wo^T + b), f_atoms fp32 fused ----------
// 128-col slices XCD-paired (A reads duplicated across halves -> share via L2).
__global__ __launch_bounds__(512, 2)
void gemm_ro(const u16* __restrict__ A1, const float* __restrict__ A2,
             const u16* __restrict__ Bt, int M,
             const float* __restrict__ bias, float* __restrict__ outf) {
    constexpr int KPAD = 448, KSPLIT = 256, K2 = 192, KMAX2 = 133;
    constexpr int LSTR = KPAD + 8;
    constexpr int NROWS = 128;
    __shared__ u16 Bs[NROWS * LSTR];
    const int tid = threadIdx.x;
    const int wave = tid >> 6;
    const int lane = tid & 63;
    const int mrow = lane & 15;
    const int quad = lane >> 4;

    const int nch = (M + 255) >> 8;
    const int cpx = (nch + 7) >> 3;
    const int bid = blockIdx.x;
    const int xcd = bid & 7;
    const int seq = bid >> 3;
    const long chunk = (long)xcd * cpx + (seq >> 1);
    if (chunk >= nch) return;
    const int nbase = (seq & 1) * NROWS;

    constexpr int KC = KPAD / 8;
    for (int i = tid; i < NROWS * KC; i += 512) {
        int r = i / KC, kc = i % KC;
        *(uint4*)&Bs[r * LSTR + kc * 8] =
            *(const uint4*)&Bt[(size_t)(nbase + r) * KPAD + kc * 8];
    }
    __syncthreads();

    const long mbase = chunk * 256 + wave * 32;
    long row[2];
#pragma unroll
    for (int t = 0; t < 2; ++t) {
        long r = mbase + t * 16 + mrow;
        if (r >= M) r = M - 1;
        row[t] = r;
    }

    f32x4v acc[2][8];
#pragma unroll
    for (int t = 0; t < 2; ++t)
#pragma unroll
        for (int j = 0; j < 8; ++j) acc[t][j] = (f32x4v){0.f, 0.f, 0.f, 0.f};

#pragma unroll 2
    for (int k0 = 0; k0 < KSPLIT; k0 += 32) {
        bf16x8v a_frag[2], b_frag[8];
#pragma unroll
        for (int t = 0; t < 2; ++t)
            a_frag[t] = *(const bf16x8v*)&A1[row[t] * KSPLIT + k0 + quad * 8];
#pragma unroll
        for (int j = 0; j < 8; ++j)
            b_frag[j] = *(const bf16x8v*)&Bs[(j * 16 + mrow) * LSTR + k0 + quad * 8];
#pragma unroll
        for (int t = 0; t < 2; ++t)
#pragma unroll
            for (int j = 0; j < 8; ++j)
                acc[t][j] = __builtin_amdgcn_mfma_f32_16x16x32_bf16(
                    a_frag[t], b_frag[j], acc[t][j], 0, 0, 0);
    }
#pragma unroll 2
    for (int k0 = 0; k0 < K2; k0 += 32) {
        bf16x8v a_frag[2], b_frag[8];
#pragma unroll
        for (int t = 0; t < 2; ++t)
            a_frag[t] = load_cvt8(A2 + row[t] * KMAX2, k0 + quad * 8, KMAX2);
#pragma unroll
        for (int j = 0; j < 8; ++j)
            b_frag[j] = *(const bf16x8v*)&Bs[(j * 16 + mrow) * LSTR + KSPLIT + k0 + quad * 8];
#pragma unroll
        for (int t = 0; t < 2; ++t)
#pragma unroll
            for (int j = 0; j < 8; ++j)
                acc[t][j] = __builtin_amdgcn_mfma_f32_16x16x32_bf16(
                    a_frag[t], b_frag[j], acc[t][j], 0, 0, 0);
    }

#pragma unroll
    for (int t = 0; t < 2; ++t)
#pragma unroll
        for (int r = 0; r < 4; ++r) {
            long grow = mbase + t * 16 + quad * 4 + r;
            if (grow < M)
#pragma unroll
                for (int j = 0; j < 8; ++j) {
                    int gcol = nbase + j * 16 + mrow;
                    float s = acc[t][j][r] + bias[gcol];
                    outf[(size_t)grow * 256 + gcol] = s > 0.f ? s : 0.f;
                }
        }
}

// ---------- per-molecule weighted mean (mol_ids sorted) ----------
__global__ __launch_bounds__(256)
void aggregate_kernel(const float* __restrict__ hid, const float* __restrict__ w_atoms,
                      const int* __restrict__ mol_ids, const float* __restrict__ deg,
                      float* __restrict__ out, int nAtoms) {
    int m = blockIdx.x;
    int t = threadIdx.x;
    int lo = 0, hi = nAtoms;
    while (lo < hi) { int mid = (lo + hi) >> 1; if (mol_ids[mid] < m) lo = mid + 1; else hi = mid; }
    int start = lo;
    lo = start; hi = nAtoms;
    while (lo < hi) { int mid = (lo + hi) >> 1; if (mol_ids[mid] < m + 1) lo = mid + 1; else hi = mid; }
    int end = lo;
    float acc = 0.f, wsum = 0.f;
    for (int a = start; a < end; ++a) {
        float w = w_atoms[a];
        wsum += w;
        acc += w * hid[(size_t)a * 256 + t];
    }
    float res = (wsum > 0.f) ? deg[m] * acc / wsum : 0.f;
    out[m * 256 + t] = res;
}

// ---------- launch ----------
extern "C" void kernel_launch(void* const* d_in, const int* in_sizes, int n_in,
                              void* d_out, int out_size, void* d_ws, size_t ws_size,
                              hipStream_t stream) {
    const float* f_atoms = (const float*)d_in[0];
    const float* f_bonds = (const float*)d_in[1];
    const float* w_atoms = (const float*)d_in[2];
    const float* w_bonds = (const float*)d_in[3];
    const float* W_i     = (const float*)d_in[4];
    const float* W_h     = (const float*)d_in[5];
    const float* W_o     = (const float*)d_in[6];
    const float* b_o     = (const float*)d_in[7];
    const float* deg     = (const float*)d_in[8];
    const int*   a2b     = (const int*)d_in[9];
    const int*   b2a     = (const int*)d_in[10];
    const int*   b2revb  = (const int*)d_in[11];
    const int*   mol_ids = (const int*)d_in[12];
    float* out = (float*)d_out;

    const int nB = 250000, nA = 100000, nM = 2000;

    // ws layout (bytes):
    //  P0 @ 0     : inp bf16 [250k][256] = 128 MB (becomes msgB in-place after iter-1 GEMM)
    //  P1 @ 128M  : msgA bf16 [250k][256] = 128 MB
    //  P2 @ 256M  : hid fp32 [100k][256] = 102.4 MB
    //  P3 @ 384M  : amsg bf16 [100k][256] = 51.2 MB
    //  P4 @ 435.2M: Wt_i (81,920) | Wt_h (131,072) | Wt_o (229,376)
    char* ws = (char*)d_ws;
    u16* inp    = (u16*)(ws);
    u16* msgA   = (u16*)(ws + 128000000L);
    float* hid  = (float*)(ws + 256000000L);
    u16* amsg   = (u16*)(ws + 384000000L);
    u16* wt_i   = (u16*)(ws + 435200000L);
    u16* wt_h   = (u16*)(ws + 435200000L + 81920L);
    u16* wt_o   = (u16*)(ws + 435200000L + 81920L + 131072L);

    if (ws_size < 435642368UL) return;

    dim3 b256(256), b512(512), b1024(1024);
    pack_all<<<dim3((256 * 160 + 256 * 256 + 256 * 448 + 255) / 256), b256, 0, stream>>>(
        W_i, W_h, W_o, wt_i, wt_h, wt_o);

    // GEMM1: inp = f_bonds @ W_i^T (fp32 A, conversion fused)
    gemm_in<<<dim3(977), b512, 0, stream>>>(f_bonds, wt_i, nB, inp);

    // gemm_mp grid: 128 rows per 1024-thread block
    dim3 gmp((nB + 127) / 128);
    const int nchA = (nA + 255) >> 8, cpxA = (nchA + 7) >> 3;
    dim3 gro(8 * cpxA * 2);

    // iteration 0 (msg == relu(inp) on the fly everywhere)
    gather16<true><<<dim3((nA + 15) / 16), b256, 0, stream>>>(inp, a2b, w_bonds, amsg, nA);
    gemm_mp<true><<<gmp, b1024, 0, stream>>>(
        amsg, inp, b2a, b2revb, wt_h, nB, inp, msgA);

    // iteration 1
    gather16<false><<<dim3((nA + 15) / 16), b256, 0, stream>>>(msgA, a2b, w_bonds, amsg, nA);
    gemm_mp<false><<<gmp, b1024, 0, stream>>>(
        amsg, msgA, b2a, b2revb, wt_h, nB, inp, inp);   // msgB in-place over inp

    // final readout
    gather16<false><<<dim3((nA + 15) / 16), b256, 0, stream>>>(inp /*msgB*/, a2b, w_bonds, amsg, nA);
    gemm_ro<<<gro, b512, 0, stream>>>(amsg, f_atoms, wt_o, nA, b_o, hid);

    aggregate_kernel<<<dim3(nM), b256, 0, stream>>>(hid, w_atoms, mol_ids, deg, out, nA);
}

// Round 6
// 851.065 us; speedup vs baseline: 1.2940x; 1.0079x over previous
//
#include <hip/hip_runtime.h>
#include <hip/hip_bf16.h>

typedef unsigned short u16;
typedef __bf16 bf16x8v __attribute__((ext_vector_type(8)));
typedef float f32x4v __attribute__((ext_vector_type(4)));
typedef float f32x4u __attribute__((ext_vector_type(4))) __attribute__((aligned(4)));

// ---------- bf16 helpers (RNE) ----------
__device__ __forceinline__ float bf2f(u16 u) {
    union { float f; unsigned int i; } c; c.i = ((unsigned int)u) << 16; return c.f;
}
__device__ __forceinline__ u16 f2bf(float f) {
    union { float f; unsigned int i; } c; c.f = f;
    unsigned int i = c.i;
    unsigned int lsb = (i >> 16) & 1u;
    i += 0x7fffu + lsb;
    return (u16)(i >> 16);
}
__device__ __forceinline__ float lo16(unsigned u) { return bf2f((u16)(u & 0xffff)); }
__device__ __forceinline__ float hi16(unsigned u) { return bf2f((u16)(u >> 16)); }
__device__ __forceinline__ unsigned pack2(float lo, float hi) {
    return (unsigned)f2bf(lo) | ((unsigned)f2bf(hi) << 16);
}

// packed-bf16 bit tricks:
//   neg2:      x -> -x
//   relu_neg2: x -> -relu(x)
__device__ __forceinline__ unsigned neg2(unsigned u) { return u ^ 0x80008000u; }
__device__ __forceinline__ unsigned relu_neg2(unsigned u) {
    unsigned s = u & 0x80008000u;
    unsigned m = (s - (s >> 15)) | s;      // 0xffff per negative half
    return (u ^ 0x80008000u) & ~m;
}

// load 8 fp32 from rowp[k..k+7] (guarded, zero-padded), convert to bf16x8 fragment
__device__ __forceinline__ bf16x8v load_cvt8(const float* __restrict__ rowp, int k, int kmax) {
    union { unsigned u[4]; bf16x8v v; } r;
#pragma unroll
    for (int g = 0; g < 2; ++g) {
        int kk = k + g * 4;
        float f0, f1, f2, f3;
        if (kk + 3 < kmax) {
            f32x4u q = *(const f32x4u*)(rowp + kk);
            f0 = q.x; f1 = q.y; f2 = q.z; f3 = q.w;
        } else {
            f0 = (kk + 0 < kmax) ? rowp[kk + 0] : 0.f;
            f1 = (kk + 1 < kmax) ? rowp[kk + 1] : 0.f;
            f2 = (kk + 2 < kmax) ? rowp[kk + 2] : 0.f;
            f3 = (kk + 3 < kmax) ? rowp[kk + 3] : 0.f;
        }
        r.u[g * 2]     = pack2(f0, f1);
        r.u[g * 2 + 1] = pack2(f2, f3);
    }
    return r.v;
}

// ---------- all weight packing in ONE dispatch ----------
__global__ __launch_bounds__(256)
void pack_all(const float* __restrict__ W_i, const float* __restrict__ W_h,
              const float* __restrict__ W_o,
              u16* __restrict__ wti, u16* __restrict__ wth, u16* __restrict__ wto) {
    int idx = blockIdx.x * 256 + threadIdx.x;
    if (idx < 256 * 160) {
        int n = idx / 160, k = idx % 160;
        wti[idx] = f2bf(k < 147 ? W_i[k * 256 + n] : 0.f);
        return;
    }
    idx -= 256 * 160;
    if (idx < 256 * 256) {
        int n = idx / 256, k = idx % 256;
        wth[idx] = f2bf(W_h[k * 256 + n]);
        return;
    }
    idx -= 256 * 256;
    if (idx < 256 * 448) {
        int n = idx / 448, k = idx % 448;
        float v;
        if (k < 256)       v = W_o[(133 + k) * 256 + n];
        else if (k < 389)  v = W_o[(k - 256) * 256 + n];
        else               v = 0.f;
        wto[idx] = f2bf(v);
    }
}

// ---------- gather (2 atoms/thread, 12 independent 16B loads in flight) ----------
template <bool RELU>
__global__ __launch_bounds__(256)
void gather16(const u16* __restrict__ msg, const int* __restrict__ a2b,
              const float* __restrict__ w_bonds, u16* __restrict__ out, int nAtoms) {
    int t = threadIdx.x;
    int g = t >> 5;                       // 0..7
    int co = (t & 31) * 8;
    int atom0 = blockIdx.x * 16 + g;
    int atom1 = atom0 + 8;
    if (atom1 >= nAtoms) { if (atom0 >= nAtoms) return; atom1 = atom0; }

    int bidx[12];
#pragma unroll
    for (int j = 0; j < 6; ++j) {
        bidx[j]     = a2b[atom0 * 6 + j];
        bidx[6 + j] = a2b[atom1 * 6 + j];
    }
    float w[12];
#pragma unroll
    for (int j = 0; j < 12; ++j) w[j] = w_bonds[bidx[j]];
    uint4 v[12];
#pragma unroll
    for (int j = 0; j < 12; ++j)
        v[j] = *(const uint4*)(msg + (size_t)bidx[j] * 256 + co);

    float a0[8] = {0,0,0,0,0,0,0,0}, a1[8] = {0,0,0,0,0,0,0,0};
#pragma unroll
    for (int j = 0; j < 6; ++j) {
        unsigned p[4] = {v[j].x, v[j].y, v[j].z, v[j].w};
        unsigned q[4] = {v[6+j].x, v[6+j].y, v[6+j].z, v[6+j].w};
#pragma unroll
        for (int c = 0; c < 4; ++c) {
            float m0 = lo16(p[c]), m1 = hi16(p[c]);
            float n0 = lo16(q[c]), n1 = hi16(q[c]);
            if (RELU) {
                m0 = fmaxf(m0, 0.f); m1 = fmaxf(m1, 0.f);
                n0 = fmaxf(n0, 0.f); n1 = fmaxf(n1, 0.f);
            }
            a0[c * 2]     += w[j] * m0;
            a0[c * 2 + 1] += w[j] * m1;
            a1[c * 2]     += w[6+j] * n0;
            a1[c * 2 + 1] += w[6+j] * n1;
        }
    }
    uint4 o0, o1;
    o0.x = pack2(a0[0], a0[1]); o0.y = pack2(a0[2], a0[3]);
    o0.z = pack2(a0[4], a0[5]); o0.w = pack2(a0[6], a0[7]);
    o1.x = pack2(a1[0], a1[1]); o1.y = pack2(a1[2], a1[3]);
    o1.z = pack2(a1[4], a1[5]); o1.w = pack2(a1[6], a1[7]);
    *(uint4*)(out + (size_t)atom0 * 256 + co) = o0;
    if (atom1 != atom0)
        *(uint4*)(out + (size_t)atom1 * 256 + co) = o1;
}

// ---------- GEMM1: inp = f_bonds(fp32, stride 147) @ W_i^T, conversion fused into A-load ----------
__global__ __launch_bounds__(512, 2)
void gemm_in(const float* __restrict__ A, const u16* __restrict__ Bt, int M,
             u16* __restrict__ out0) {
    constexpr int KPAD = 160, KMAX = 147, ASTR = 147;
    constexpr int LSTR = KPAD + 8;
    __shared__ u16 Bs[256 * LSTR];
    const int tid = threadIdx.x;
    const int wave = tid >> 6;
    const int lane = tid & 63;
    const int mrow = lane & 15;
    const int quad = lane >> 4;

    constexpr int KC = KPAD / 8;
    for (int i = tid; i < 256 * KC; i += 512) {
        int r = i / KC, kc = i % KC;
        *(uint4*)&Bs[r * LSTR + kc * 8] = *(const uint4*)&Bt[(size_t)r * KPAD + kc * 8];
    }
    __syncthreads();

    for (long chunk = blockIdx.x; chunk * 256 < (long)M; chunk += gridDim.x) {
        const long mbase = chunk * 256 + wave * 32;
        const float* rowp[2];
#pragma unroll
        for (int t = 0; t < 2; ++t) {
            long r = mbase + t * 16 + mrow;
            if (r >= M) r = M - 1;
            rowp[t] = A + r * ASTR;
        }

        f32x4v acc[2][16];
#pragma unroll
        for (int t = 0; t < 2; ++t)
#pragma unroll
            for (int j = 0; j < 16; ++j) acc[t][j] = (f32x4v){0.f, 0.f, 0.f, 0.f};

#pragma unroll 2
        for (int k0 = 0; k0 < KPAD; k0 += 32) {
            bf16x8v a_frag[2];
#pragma unroll
            for (int t = 0; t < 2; ++t)
                a_frag[t] = load_cvt8(rowp[t], k0 + quad * 8, KMAX);
#pragma unroll
            for (int jg = 0; jg < 4; ++jg) {
                bf16x8v b_frag[4];
#pragma unroll
                for (int j4 = 0; j4 < 4; ++j4)
                    b_frag[j4] = *(const bf16x8v*)&Bs[((jg * 4 + j4) * 16 + mrow) * LSTR + k0 + quad * 8];
#pragma unroll
                for (int t = 0; t < 2; ++t)
#pragma unroll
                    for (int j4 = 0; j4 < 4; ++j4)
                        acc[t][jg * 4 + j4] = __builtin_amdgcn_mfma_f32_16x16x32_bf16(
                            a_frag[t], b_frag[j4], acc[t][jg * 4 + j4], 0, 0, 0);
            }
        }

#pragma unroll
        for (int t = 0; t < 2; ++t)
#pragma unroll
            for (int r = 0; r < 4; ++r) {
                long grow = mbase + t * 16 + quad * 4 + r;
                if (grow < M)
#pragma unroll
                    for (int j = 0; j < 16; ++j)
                        out0[(size_t)grow * 256 + j * 16 + mrow] = f2bf(acc[t][j][r]);
            }
    }
}

// ---------- fused message-passing GEMM (1024 thr, N-split, XCD-paired, 2 blocks/CU) ----------
// msg_new[b][:] = relu( inp[b] + (amsg[b2a[b]] - relu?(msgsrc[b2revb[b]])) @ Wh^T )
// (a - relu(r)) @ W = a @ W + (-relu(r)) @ W  -> dual MFMA, A raw bf16.
// Block = 256 bond rows x 128-col half; 16 waves, wave = 16 rows x 128 cols, acc[8]=32 VGPR.
// LDS 67.6 KB + VGPR<=64 (launch_bounds(1024,8)) -> 2 blocks/CU = 32 waves/CU:
// 2x wave concurrency of all prior rounds to hide gather latency (R5 diagnosis:
// everything pinned at ~37% = concurrency-starved).
// XCD-paired halves (R2-proven): duplicate half's gathers L2-dedup (FETCH ~1x) and
// 256B half-line writes combine in XCD-L2 (WRITE ~1x).
template <bool RELUV>
__global__ __launch_bounds__(1024, 8)
void gemm_mp(const u16* __restrict__ amsg, const u16* __restrict__ msgsrc,
             const int* __restrict__ b2a, const int* __restrict__ b2revb,
             const u16* __restrict__ Bt, int M,
             const u16* __restrict__ inp, u16* __restrict__ out0) {
    constexpr int KPAD = 256;
    constexpr int LSTR = KPAD + 8;
    constexpr int NROWS = 128;                 // N-half per block
    __shared__ u16 Bs[NROWS * LSTR];           // 67584 B -> 2 blocks/CU
    const int tid = threadIdx.x;
    const int wave = tid >> 6;                 // 0..15 row group
    const int lane = tid & 63;
    const int mrow = lane & 15;
    const int quad = lane >> 4;

    const int nch = (M + 255) >> 8;            // 256-row chunks
    const int cpx = (nch + 7) >> 3;            // chunks per XCD
    const int bid = blockIdx.x;
    const int xcd = bid & 7;
    const int seq = bid >> 3;
    const long chunk = (long)xcd * cpx + (seq >> 1);
    if (chunk >= nch) return;                  // uniform pre-barrier exit
    const int nbase = (seq & 1) * NROWS;

    for (int i = tid; i < NROWS * 32; i += 1024) {
        int r = i >> 5, kc = i & 31;
        *(uint4*)&Bs[r * LSTR + kc * 8] = *(const uint4*)&Bt[(size_t)(nbase + r) * KPAD + kc * 8];
    }
    __syncthreads();

    const long mbase = chunk * 256 + wave * 16;
    long b = mbase + mrow;
    if (b >= M) b = M - 1;
    const size_t soff = (size_t)b2a[b] * 256 + quad * 8;
    const size_t roff = (size_t)b2revb[b] * 256 + quad * 8;

    f32x4v acc[8];
#pragma unroll
    for (int j = 0; j < 8; ++j) acc[j] = (f32x4v){0.f, 0.f, 0.f, 0.f};

#pragma unroll 2
    for (int k0 = 0; k0 < KPAD; k0 += 32) {
        uint4 va = *(const uint4*)&amsg[soff + k0];
        uint4 vr = *(const uint4*)&msgsrc[roff + k0];
        union { uint4 q; bf16x8v v; } ua, ur;
        ua.q = va;
        if (RELUV) {
            ur.q.x = relu_neg2(vr.x); ur.q.y = relu_neg2(vr.y);
            ur.q.z = relu_neg2(vr.z); ur.q.w = relu_neg2(vr.w);
        } else {
            ur.q.x = neg2(vr.x); ur.q.y = neg2(vr.y);
            ur.q.z = neg2(vr.z); ur.q.w = neg2(vr.w);
        }
#pragma unroll
        for (int j = 0; j < 8; ++j) {
            bf16x8v b_frag = *(const bf16x8v*)&Bs[(j * 16 + mrow) * LSTR + k0 + quad * 8];
            acc[j] = __builtin_amdgcn_mfma_f32_16x16x32_bf16(ua.v, b_frag, acc[j], 0, 0, 0);
            acc[j] = __builtin_amdgcn_mfma_f32_16x16x32_bf16(ur.v, b_frag, acc[j], 0, 0, 0);
        }
    }

    // epilogue: msg_new = relu(inp + acc)  (out0 may alias inp: own-idx read-then-write,
    // halves touch disjoint columns)
#pragma unroll
    for (int r = 0; r < 4; ++r) {
        long grow = mbase + quad * 4 + r;
        if (grow < M)
#pragma unroll
            for (int j = 0; j < 8; ++j) {
                size_t idx = (size_t)grow * 256 + nbase + j * 16 + mrow;
                float s = bf2f(inp[idx]) + acc[j][r];
                out0[idx] = f2bf(s > 0.f ? s : 0.f);
            }
    }
}

// ---------- readout GEMM: hid = relu([amsg | f_atoms] @ Wo^T + b), f_atoms fp32 fused ----------
// 128-col slices XCD-paired (A reads duplicated across halves -> share via L2).
__global__ __launch_bounds__(512, 2)
void gemm_ro(const u16* __restrict__ A1, const float* __restrict__ A2,
             const u16* __restrict__ Bt, int M,
             const float* __restrict__ bias, float* __restrict__ outf) {
    constexpr int KPAD = 448, KSPLIT = 256, K2 = 192, KMAX2 = 133;
    constexpr int LSTR = KPAD + 8;
    constexpr int NROWS = 128;
    __shared__ u16 Bs[NROWS * LSTR];
    const int tid = threadIdx.x;
    const int wave = tid >> 6;
    const int lane = tid & 63;
    const int mrow = lane & 15;
    const int quad = lane >> 4;

    const int nch = (M + 255) >> 8;
    const int cpx = (nch + 7) >> 3;
    const int bid = blockIdx.x;
    const int xcd = bid & 7;
    const int seq = bid >> 3;
    const long chunk = (long)xcd * cpx + (seq >> 1);
    if (chunk >= nch) return;
    const int nbase = (seq & 1) * NROWS;

    constexpr int KC = KPAD / 8;
    for (int i = tid; i < NROWS * KC; i += 512) {
        int r = i / KC, kc = i % KC;
        *(uint4*)&Bs[r * LSTR + kc * 8] =
            *(const uint4*)&Bt[(size_t)(nbase + r) * KPAD + kc * 8];
    }
    __syncthreads();

    const long mbase = chunk * 256 + wave * 32;
    long row[2];
#pragma unroll
    for (int t = 0; t < 2; ++t) {
        long r = mbase + t * 16 + mrow;
        if (r >= M) r = M - 1;
        row[t] = r;
    }

    f32x4v acc[2][8];
#pragma unroll
    for (int t = 0; t < 2; ++t)
#pragma unroll
        for (int j = 0; j < 8; ++j) acc[t][j] = (f32x4v){0.f, 0.f, 0.f, 0.f};

#pragma unroll 2
    for (int k0 = 0; k0 < KSPLIT; k0 += 32) {
        bf16x8v a_frag[2], b_frag[8];
#pragma unroll
        for (int t = 0; t < 2; ++t)
            a_frag[t] = *(const bf16x8v*)&A1[row[t] * KSPLIT + k0 + quad * 8];
#pragma unroll
        for (int j = 0; j < 8; ++j)
            b_frag[j] = *(const bf16x8v*)&Bs[(j * 16 + mrow) * LSTR + k0 + quad * 8];
#pragma unroll
        for (int t = 0; t < 2; ++t)
#pragma unroll
            for (int j = 0; j < 8; ++j)
                acc[t][j] = __builtin_amdgcn_mfma_f32_16x16x32_bf16(
                    a_frag[t], b_frag[j], acc[t][j], 0, 0, 0);
    }
#pragma unroll 2
    for (int k0 = 0; k0 < K2; k0 += 32) {
        bf16x8v a_frag[2], b_frag[8];
#pragma unroll
        for (int t = 0; t < 2; ++t)
            a_frag[t] = load_cvt8(A2 + row[t] * KMAX2, k0 + quad * 8, KMAX2);
#pragma unroll
        for (int j = 0; j < 8; ++j)
            b_frag[j] = *(const bf16x8v*)&Bs[(j * 16 + mrow) * LSTR + KSPLIT + k0 + quad * 8];
#pragma unroll
        for (int t = 0; t < 2; ++t)
#pragma unroll
            for (int j = 0; j < 8; ++j)
                acc[t][j] = __builtin_amdgcn_mfma_f32_16x16x32_bf16(
                    a_frag[t], b_frag[j], acc[t][j], 0, 0, 0);
    }

#pragma unroll
    for (int t = 0; t < 2; ++t)
#pragma unroll
        for (int r = 0; r < 4; ++r) {
            long grow = mbase + t * 16 + quad * 4 + r;
            if (grow < M)
#pragma unroll
                for (int j = 0; j < 8; ++j) {
                    int gcol = nbase + j * 16 + mrow;
                    float s = acc[t][j][r] + bias[gcol];
                    outf[(size_t)grow * 256 + gcol] = s > 0.f ? s : 0.f;
                }
        }
}

// ---------- per-molecule weighted mean (mol_ids sorted) ----------
__global__ __launch_bounds__(256)
void aggregate_kernel(const float* __restrict__ hid, const float* __restrict__ w_atoms,
                      const int* __restrict__ mol_ids, const float* __restrict__ deg,
                      float* __restrict__ out, int nAtoms) {
    int m = blockIdx.x;
    int t = threadIdx.x;
    int lo = 0, hi = nAtoms;
    while (lo < hi) { int mid = (lo + hi) >> 1; if (mol_ids[mid] < m) lo = mid + 1; else hi = mid; }
    int start = lo;
    lo = start; hi = nAtoms;
    while (lo < hi) { int mid = (lo + hi) >> 1; if (mol_ids[mid] < m + 1) lo = mid + 1; else hi = mid; }
    int end = lo;
    float acc = 0.f, wsum = 0.f;
    for (int a = start; a < end; ++a) {
        float w = w_atoms[a];
        wsum += w;
        acc += w * hid[(size_t)a * 256 + t];
    }
    float res = (wsum > 0.f) ? deg[m] * acc / wsum : 0.f;
    out[m * 256 + t] = res;
}

// ---------- launch ----------
extern "C" void kernel_launch(void* const* d_in, const int* in_sizes, int n_in,
                              void* d_out, int out_size, void* d_ws, size_t ws_size,
                              hipStream_t stream) {
    const float* f_atoms = (const float*)d_in[0];
    const float* f_bonds = (const float*)d_in[1];
    const float* w_atoms = (const float*)d_in[2];
    const float* w_bonds = (const float*)d_in[3];
    const float* W_i     = (const float*)d_in[4];
    const float* W_h     = (const float*)d_in[5];
    const float* W_o     = (const float*)d_in[6];
    const float* b_o     = (const float*)d_in[7];
    const float* deg     = (const float*)d_in[8];
    const int*   a2b     = (const int*)d_in[9];
    const int*   b2a     = (const int*)d_in[10];
    const int*   b2revb  = (const int*)d_in[11];
    const int*   mol_ids = (const int*)d_in[12];
    float* out = (float*)d_out;

    const int nB = 250000, nA = 100000, nM = 2000;

    // ws layout (bytes):
    //  P0 @ 0     : inp bf16 [250k][256] = 128 MB (becomes msgB in-place after iter-1 GEMM)
    //  P1 @ 128M  : msgA bf16 [250k][256] = 128 MB
    //  P2 @ 256M  : hid fp32 [100k][256] = 102.4 MB
    //  P3 @ 384M  : amsg bf16 [100k][256] = 51.2 MB
    //  P4 @ 435.2M: Wt_i (81,920) | Wt_h (131,072) | Wt_o (229,376)
    char* ws = (char*)d_ws;
    u16* inp    = (u16*)(ws);
    u16* msgA   = (u16*)(ws + 128000000L);
    float* hid  = (float*)(ws + 256000000L);
    u16* amsg   = (u16*)(ws + 384000000L);
    u16* wt_i   = (u16*)(ws + 435200000L);
    u16* wt_h   = (u16*)(ws + 435200000L + 81920L);
    u16* wt_o   = (u16*)(ws + 435200000L + 81920L + 131072L);

    if (ws_size < 435642368UL) return;

    dim3 b256(256), b512(512), b1024(1024);
    pack_all<<<dim3((256 * 160 + 256 * 256 + 256 * 448 + 255) / 256), b256, 0, stream>>>(
        W_i, W_h, W_o, wt_i, wt_h, wt_o);

    // GEMM1: inp = f_bonds @ W_i^T (fp32 A, conversion fused)
    gemm_in<<<dim3(977), b512, 0, stream>>>(f_bonds, wt_i, nB, inp);

    // gemm_mp grid: 256-row chunks, 8 XCDs * cpx * 2 halves
    const int nchB = (nB + 255) >> 8, cpxB = (nchB + 7) >> 3;
    dim3 gmp(8 * cpxB * 2);
    const int nchA = (nA + 255) >> 8, cpxA = (nchA + 7) >> 3;
    dim3 gro(8 * cpxA * 2);

    // iteration 0 (msg == relu(inp) on the fly everywhere)
    gather16<true><<<dim3((nA + 15) / 16), b256, 0, stream>>>(inp, a2b, w_bonds, amsg, nA);
    gemm_mp<true><<<gmp, b1024, 0, stream>>>(
        amsg, inp, b2a, b2revb, wt_h, nB, inp, msgA);

    // iteration 1
    gather16<false><<<dim3((nA + 15) / 16), b256, 0, stream>>>(msgA, a2b, w_bonds, amsg, nA);
    gemm_mp<false><<<gmp, b1024, 0, stream>>>(
        amsg, msgA, b2a, b2revb, wt_h, nB, inp, inp);   // msgB in-place over inp

    // final readout
    gather16<false><<<dim3((nA + 15) / 16), b256, 0, stream>>>(inp /*msgB*/, a2b, w_bonds, amsg, nA);
    gemm_ro<<<gro, b512, 0, stream>>>(amsg, f_atoms, wt_o, nA, b_o, hid);

    aggregate_kernel<<<dim3(nM), b256, 0, stream>>>(hid, w_atoms, mol_ids, deg, out, nA);
}

// Round 7
// 845.096 us; speedup vs baseline: 1.3032x; 1.0071x over previous
//
#include <hip/hip_runtime.h>
#include <hip/hip_bf16.h>

typedef unsigned short u16;
typedef __bf16 bf16x8v __attribute__((ext_vector_type(8)));
typedef float f32x4v __attribute__((ext_vector_type(4)));
typedef float f32x4u __attribute__((ext_vector_type(4))) __attribute__((aligned(4)));

// ---------- bf16 helpers (RNE) ----------
__device__ __forceinline__ float bf2f(u16 u) {
    union { float f; unsigned int i; } c; c.i = ((unsigned int)u) << 16; return c.f;
}
__device__ __forceinline__ u16 f2bf(float f) {
    union { float f; unsigned int i; } c; c.f = f;
    unsigned int i = c.i;
    unsigned int lsb = (i >> 16) & 1u;
    i += 0x7fffu + lsb;
    return (u16)(i >> 16);
}
__device__ __forceinline__ float lo16(unsigned u) { return bf2f((u16)(u & 0xffff)); }
__device__ __forceinline__ float hi16(unsigned u) { return bf2f((u16)(u >> 16)); }
__device__ __forceinline__ unsigned pack2(float lo, float hi) {
    return (unsigned)f2bf(lo) | ((unsigned)f2bf(hi) << 16);
}

// packed-bf16 bit tricks:
//   neg2:      x -> -x
//   relu_neg2: x -> -relu(x)
__device__ __forceinline__ unsigned neg2(unsigned u) { return u ^ 0x80008000u; }
__device__ __forceinline__ unsigned relu_neg2(unsigned u) {
    unsigned s = u & 0x80008000u;
    unsigned m = (s - (s >> 15)) | s;      // 0xffff per negative half
    return (u ^ 0x80008000u) & ~m;
}

// load 8 fp32 from rowp[k..k+7] (guarded, zero-padded), convert to bf16x8 fragment
__device__ __forceinline__ bf16x8v load_cvt8(const float* __restrict__ rowp, int k, int kmax) {
    union { unsigned u[4]; bf16x8v v; } r;
#pragma unroll
    for (int g = 0; g < 2; ++g) {
        int kk = k + g * 4;
        float f0, f1, f2, f3;
        if (kk + 3 < kmax) {
            f32x4u q = *(const f32x4u*)(rowp + kk);
            f0 = q.x; f1 = q.y; f2 = q.z; f3 = q.w;
        } else {
            f0 = (kk + 0 < kmax) ? rowp[kk + 0] : 0.f;
            f1 = (kk + 1 < kmax) ? rowp[kk + 1] : 0.f;
            f2 = (kk + 2 < kmax) ? rowp[kk + 2] : 0.f;
            f3 = (kk + 3 < kmax) ? rowp[kk + 3] : 0.f;
        }
        r.u[g * 2]     = pack2(f0, f1);
        r.u[g * 2 + 1] = pack2(f2, f3);
    }
    return r.v;
}

// ---------- all weight packing + mol_sum zeroing in ONE dispatch ----------
// ranges: [0,40960) Wt_i | [..,106496) Wt_h | [..,221184) Wt_o | [..,733184) mol_sum=0
__global__ __launch_bounds__(256)
void pack_all(const float* __restrict__ W_i, const float* __restrict__ W_h,
              const float* __restrict__ W_o,
              u16* __restrict__ wti, u16* __restrict__ wth, u16* __restrict__ wto,
              float* __restrict__ mol_sum) {
    int idx = blockIdx.x * 256 + threadIdx.x;
    if (idx < 256 * 160) {
        int n = idx / 160, k = idx % 160;
        wti[idx] = f2bf(k < 147 ? W_i[k * 256 + n] : 0.f);
        return;
    }
    idx -= 256 * 160;
    if (idx < 256 * 256) {
        int n = idx / 256, k = idx % 256;
        wth[idx] = f2bf(W_h[k * 256 + n]);
        return;
    }
    idx -= 256 * 256;
    if (idx < 256 * 448) {
        int n = idx / 448, k = idx % 448;
        float v;
        if (k < 256)       v = W_o[(133 + k) * 256 + n];
        else if (k < 389)  v = W_o[(k - 256) * 256 + n];
        else               v = 0.f;
        wto[idx] = f2bf(v);
        return;
    }
    idx -= 256 * 448;
    if (idx < 2000 * 256) mol_sum[idx] = 0.f;
}

// ---------- gather (2 atoms/thread, 12 independent 16B loads in flight) ----------
template <bool RELU>
__global__ __launch_bounds__(256)
void gather16(const u16* __restrict__ msg, const int* __restrict__ a2b,
              const float* __restrict__ w_bonds, u16* __restrict__ out, int nAtoms) {
    int t = threadIdx.x;
    int g = t >> 5;                       // 0..7
    int co = (t & 31) * 8;
    int atom0 = blockIdx.x * 16 + g;
    int atom1 = atom0 + 8;
    if (atom1 >= nAtoms) { if (atom0 >= nAtoms) return; atom1 = atom0; }

    int bidx[12];
#pragma unroll
    for (int j = 0; j < 6; ++j) {
        bidx[j]     = a2b[atom0 * 6 + j];
        bidx[6 + j] = a2b[atom1 * 6 + j];
    }
    float w[12];
#pragma unroll
    for (int j = 0; j < 12; ++j) w[j] = w_bonds[bidx[j]];
    uint4 v[12];
#pragma unroll
    for (int j = 0; j < 12; ++j)
        v[j] = *(const uint4*)(msg + (size_t)bidx[j] * 256 + co);

    float a0[8] = {0,0,0,0,0,0,0,0}, a1[8] = {0,0,0,0,0,0,0,0};
#pragma unroll
    for (int j = 0; j < 6; ++j) {
        unsigned p[4] = {v[j].x, v[j].y, v[j].z, v[j].w};
        unsigned q[4] = {v[6+j].x, v[6+j].y, v[6+j].z, v[6+j].w};
#pragma unroll
        for (int c = 0; c < 4; ++c) {
            float m0 = lo16(p[c]), m1 = hi16(p[c]);
            float n0 = lo16(q[c]), n1 = hi16(q[c]);
            if (RELU) {
                m0 = fmaxf(m0, 0.f); m1 = fmaxf(m1, 0.f);
                n0 = fmaxf(n0, 0.f); n1 = fmaxf(n1, 0.f);
            }
            a0[c * 2]     += w[j] * m0;
            a0[c * 2 + 1] += w[j] * m1;
            a1[c * 2]     += w[6+j] * n0;
            a1[c * 2 + 1] += w[6+j] * n1;
        }
    }
    uint4 o0, o1;
    o0.x = pack2(a0[0], a0[1]); o0.y = pack2(a0[2], a0[3]);
    o0.z = pack2(a0[4], a0[5]); o0.w = pack2(a0[6], a0[7]);
    o1.x = pack2(a1[0], a1[1]); o1.y = pack2(a1[2], a1[3]);
    o1.z = pack2(a1[4], a1[5]); o1.w = pack2(a1[6], a1[7]);
    *(uint4*)(out + (size_t)atom0 * 256 + co) = o0;
    if (atom1 != atom0)
        *(uint4*)(out + (size_t)atom1 * 256 + co) = o1;
}

// ---------- GEMM1: inp = f_bonds(fp32, stride 147) @ W_i^T, conversion fused into A-load ----------
__global__ __launch_bounds__(512, 2)
void gemm_in(const float* __restrict__ A, const u16* __restrict__ Bt, int M,
             u16* __restrict__ out0) {
    constexpr int KPAD = 160, KMAX = 147, ASTR = 147;
    constexpr int LSTR = KPAD + 8;
    __shared__ u16 Bs[256 * LSTR];
    const int tid = threadIdx.x;
    const int wave = tid >> 6;
    const int lane = tid & 63;
    const int mrow = lane & 15;
    const int quad = lane >> 4;

    constexpr int KC = KPAD / 8;
    for (int i = tid; i < 256 * KC; i += 512) {
        int r = i / KC, kc = i % KC;
        *(uint4*)&Bs[r * LSTR + kc * 8] = *(const uint4*)&Bt[(size_t)r * KPAD + kc * 8];
    }
    __syncthreads();

    for (long chunk = blockIdx.x; chunk * 256 < (long)M; chunk += gridDim.x) {
        const long mbase = chunk * 256 + wave * 32;
        const float* rowp[2];
#pragma unroll
        for (int t = 0; t < 2; ++t) {
            long r = mbase + t * 16 + mrow;
            if (r >= M) r = M - 1;
            rowp[t] = A + r * ASTR;
        }

        f32x4v acc[2][16];
#pragma unroll
        for (int t = 0; t < 2; ++t)
#pragma unroll
            for (int j = 0; j < 16; ++j) acc[t][j] = (f32x4v){0.f, 0.f, 0.f, 0.f};

#pragma unroll 2
        for (int k0 = 0; k0 < KPAD; k0 += 32) {
            bf16x8v a_frag[2];
#pragma unroll
            for (int t = 0; t < 2; ++t)
                a_frag[t] = load_cvt8(rowp[t], k0 + quad * 8, KMAX);
#pragma unroll
            for (int jg = 0; jg < 4; ++jg) {
                bf16x8v b_frag[4];
#pragma unroll
                for (int j4 = 0; j4 < 4; ++j4)
                    b_frag[j4] = *(const bf16x8v*)&Bs[((jg * 4 + j4) * 16 + mrow) * LSTR + k0 + quad * 8];
#pragma unroll
                for (int t = 0; t < 2; ++t)
#pragma unroll
                    for (int j4 = 0; j4 < 4; ++j4)
                        acc[t][jg * 4 + j4] = __builtin_amdgcn_mfma_f32_16x16x32_bf16(
                            a_frag[t], b_frag[j4], acc[t][jg * 4 + j4], 0, 0, 0);
            }
        }

#pragma unroll
        for (int t = 0; t < 2; ++t)
#pragma unroll
            for (int r = 0; r < 4; ++r) {
                long grow = mbase + t * 16 + quad * 4 + r;
                if (grow < M)
#pragma unroll
                    for (int j = 0; j < 16; ++j)
                        out0[(size_t)grow * 256 + j * 16 + mrow] = f2bf(acc[t][j][r]);
            }
    }
}

// ---------- fused message-passing GEMM (R6 best: 1024 thr, N-split, XCD-paired, 2 blocks/CU) ----------
// At its measured wall (~141us, compulsory bytes, random-row request-rate bound). Unchanged.
template <bool RELUV>
__global__ __launch_bounds__(1024, 8)
void gemm_mp(const u16* __restrict__ amsg, const u16* __restrict__ msgsrc,
             const int* __restrict__ b2a, const int* __restrict__ b2revb,
             const u16* __restrict__ Bt, int M,
             const u16* __restrict__ inp, u16* __restrict__ out0) {
    constexpr int KPAD = 256;
    constexpr int LSTR = KPAD + 8;
    constexpr int NROWS = 128;                 // N-half per block
    __shared__ u16 Bs[NROWS * LSTR];           // 67584 B -> 2 blocks/CU
    const int tid = threadIdx.x;
    const int wave = tid >> 6;                 // 0..15 row group
    const int lane = tid & 63;
    const int mrow = lane & 15;
    const int quad = lane >> 4;

    const int nch = (M + 255) >> 8;            // 256-row chunks
    const int cpx = (nch + 7) >> 3;            // chunks per XCD
    const int bid = blockIdx.x;
    const int xcd = bid & 7;
    const int seq = bid >> 3;
    const long chunk = (long)xcd * cpx + (seq >> 1);
    if (chunk >= nch) return;                  // uniform pre-barrier exit
    const int nbase = (seq & 1) * NROWS;

    for (int i = tid; i < NROWS * 32; i += 1024) {
        int r = i >> 5, kc = i & 31;
        *(uint4*)&Bs[r * LSTR + kc * 8] = *(const uint4*)&Bt[(size_t)(nbase + r) * KPAD + kc * 8];
    }
    __syncthreads();

    const long mbase = chunk * 256 + wave * 16;
    long b = mbase + mrow;
    if (b >= M) b = M - 1;
    const size_t soff = (size_t)b2a[b] * 256 + quad * 8;
    const size_t roff = (size_t)b2revb[b] * 256 + quad * 8;

    f32x4v acc[8];
#pragma unroll
    for (int j = 0; j < 8; ++j) acc[j] = (f32x4v){0.f, 0.f, 0.f, 0.f};

#pragma unroll 2
    for (int k0 = 0; k0 < KPAD; k0 += 32) {
        uint4 va = *(const uint4*)&amsg[soff + k0];
        uint4 vr = *(const uint4*)&msgsrc[roff + k0];
        union { uint4 q; bf16x8v v; } ua, ur;
        ua.q = va;
        if (RELUV) {
            ur.q.x = relu_neg2(vr.x); ur.q.y = relu_neg2(vr.y);
            ur.q.z = relu_neg2(vr.z); ur.q.w = relu_neg2(vr.w);
        } else {
            ur.q.x = neg2(vr.x); ur.q.y = neg2(vr.y);
            ur.q.z = neg2(vr.z); ur.q.w = neg2(vr.w);
        }
#pragma unroll
        for (int j = 0; j < 8; ++j) {
            bf16x8v b_frag = *(const bf16x8v*)&Bs[(j * 16 + mrow) * LSTR + k0 + quad * 8];
            acc[j] = __builtin_amdgcn_mfma_f32_16x16x32_bf16(ua.v, b_frag, acc[j], 0, 0, 0);
            acc[j] = __builtin_amdgcn_mfma_f32_16x16x32_bf16(ur.v, b_frag, acc[j], 0, 0, 0);
        }
    }

#pragma unroll
    for (int r = 0; r < 4; ++r) {
        long grow = mbase + quad * 4 + r;
        if (grow < M)
#pragma unroll
            for (int j = 0; j < 8; ++j) {
                size_t idx = (size_t)grow * 256 + nbase + j * 16 + mrow;
                float s = bf2f(inp[idx]) + acc[j][r];
                out0[idx] = f2bf(s > 0.f ? s : 0.f);
            }
    }
}

// ---------- readout GEMM with FUSED per-molecule aggregation ----------
// hid_row = relu([amsg | f_atoms] @ Wo^T + b); then instead of materializing hid,
// atomicAdd w_atoms[row]*hid_row into mol_sum[mol_ids[row]] (fp32, 2MB, L2-resident).
// Per-lane 4-row in-register combine (mol_ids sorted -> usually same molecule).
// Two-stage LDS (K 0-255 then 256-447 reusing one 67.6KB buffer) -> 2 blocks/CU,
// 16 waves/CU (was 1 block / 8 waves at 116.7KB).
__global__ __launch_bounds__(512, 4)
void gemm_ro(const u16* __restrict__ A1, const float* __restrict__ A2,
             const u16* __restrict__ Bt, int M,
             const float* __restrict__ bias,
             const float* __restrict__ w_atoms, const int* __restrict__ mol_ids,
             float* __restrict__ mol_sum) {
    constexpr int KPAD = 448, KSPLIT = 256, K2 = 192, KMAX2 = 133;
    constexpr int LSTR = KSPLIT + 8;           // stage-1 stride (264)
    constexpr int LSTR2 = K2 + 8;              // stage-2 stride (200)
    constexpr int NROWS = 128;
    __shared__ u16 Bs[NROWS * LSTR];           // 67584 B, reused by stage 2
    const int tid = threadIdx.x;
    const int wave = tid >> 6;
    const int lane = tid & 63;
    const int mrow = lane & 15;
    const int quad = lane >> 4;

    const int nch = (M + 255) >> 8;
    const int cpx = (nch + 7) >> 3;
    const int bid = blockIdx.x;
    const int xcd = bid & 7;
    const int seq = bid >> 3;
    const long chunk = (long)xcd * cpx + (seq >> 1);
    if (chunk >= nch) return;
    const int nbase = (seq & 1) * NROWS;

    // stage-1 B: K columns 0..255
    for (int i = tid; i < NROWS * 32; i += 512) {
        int r = i >> 5, kc = i & 31;
        *(uint4*)&Bs[r * LSTR + kc * 8] =
            *(const uint4*)&Bt[(size_t)(nbase + r) * KPAD + kc * 8];
    }
    __syncthreads();

    const long mbase = chunk * 256 + wave * 32;
    long row[2];
#pragma unroll
    for (int t = 0; t < 2; ++t) {
        long r = mbase + t * 16 + mrow;
        if (r >= M) r = M - 1;
        row[t] = r;
    }

    f32x4v acc[2][8];
#pragma unroll
    for (int t = 0; t < 2; ++t)
#pragma unroll
        for (int j = 0; j < 8; ++j) acc[t][j] = (f32x4v){0.f, 0.f, 0.f, 0.f};

    // K-section 1: amsg (bf16, sequential)
#pragma unroll 2
    for (int k0 = 0; k0 < KSPLIT; k0 += 32) {
        bf16x8v a_frag[2];
#pragma unroll
        for (int t = 0; t < 2; ++t)
            a_frag[t] = *(const bf16x8v*)&A1[row[t] * KSPLIT + k0 + quad * 8];
#pragma unroll
        for (int jg = 0; jg < 2; ++jg) {
            bf16x8v b_frag[4];
#pragma unroll
            for (int j4 = 0; j4 < 4; ++j4)
                b_frag[j4] = *(const bf16x8v*)&Bs[((jg * 4 + j4) * 16 + mrow) * LSTR + k0 + quad * 8];
#pragma unroll
            for (int t = 0; t < 2; ++t)
#pragma unroll
                for (int j4 = 0; j4 < 4; ++j4)
                    acc[t][jg * 4 + j4] = __builtin_amdgcn_mfma_f32_16x16x32_bf16(
                        a_frag[t], b_frag[j4], acc[t][jg * 4 + j4], 0, 0, 0);
        }
    }

    // stage-2 B: K columns 256..447 (reuse Bs with stride LSTR2)
    __syncthreads();
    for (int i = tid; i < NROWS * 24; i += 512) {
        int r = i / 24, kc = i % 24;
        *(uint4*)&Bs[r * LSTR2 + kc * 8] =
            *(const uint4*)&Bt[(size_t)(nbase + r) * KPAD + KSPLIT + kc * 8];
    }
    __syncthreads();

    // K-section 2: f_atoms (fp32 -> bf16 fused)
#pragma unroll 2
    for (int k0 = 0; k0 < K2; k0 += 32) {
        bf16x8v a_frag[2];
#pragma unroll
        for (int t = 0; t < 2; ++t)
            a_frag[t] = load_cvt8(A2 + row[t] * KMAX2, k0 + quad * 8, KMAX2);
#pragma unroll
        for (int jg = 0; jg < 2; ++jg) {
            bf16x8v b_frag[4];
#pragma unroll
            for (int j4 = 0; j4 < 4; ++j4)
                b_frag[j4] = *(const bf16x8v*)&Bs[((jg * 4 + j4) * 16 + mrow) * LSTR2 + k0 + quad * 8];
#pragma unroll
            for (int t = 0; t < 2; ++t)
#pragma unroll
                for (int j4 = 0; j4 < 4; ++j4)
                    acc[t][jg * 4 + j4] = __builtin_amdgcn_mfma_f32_16x16x32_bf16(
                        a_frag[t], b_frag[j4], acc[t][jg * 4 + j4], 0, 0, 0);
        }
    }

    // epilogue: relu(+bias), weight by w_atoms, accumulate into mol_sum via atomics.
    // 4 consecutive rows per lane -> combine equal-mol runs before the atomic.
#pragma unroll
    for (int t = 0; t < 2; ++t) {
        float w4[4]; int m4[4]; bool ok4[4];
#pragma unroll
        for (int r = 0; r < 4; ++r) {
            long grow = mbase + t * 16 + quad * 4 + r;
            ok4[r] = (grow < M);
            long gr = ok4[r] ? grow : (M - 1);
            w4[r] = w_atoms[gr];
            m4[r] = mol_ids[gr];
        }
#pragma unroll
        for (int j = 0; j < 8; ++j) {
            int gcol = nbase + j * 16 + mrow;
            float b = bias[gcol];
            float vsum = 0.f;
            int prev = -1;
#pragma unroll
            for (int r = 0; r < 4; ++r) {
                if (ok4[r]) {
                    float s = acc[t][j][r] + b;
                    s = s > 0.f ? s : 0.f;
                    float v = s * w4[r];
                    if (m4[r] != prev) {
                        if (prev >= 0) atomicAdd(&mol_sum[(size_t)prev * 256 + gcol], vsum);
                        vsum = 0.f;
                        prev = m4[r];
                    }
                    vsum += v;
                }
            }
            if (prev >= 0) atomicAdd(&mol_sum[(size_t)prev * 256 + gcol], vsum);
        }
    }
}

// ---------- finalize: out[m] = deg[m] * mol_sum[m] / wsum[m] ----------
__global__ __launch_bounds__(256)
void finalize_kernel(const float* __restrict__ mol_sum, const float* __restrict__ w_atoms,
                     const int* __restrict__ mol_ids, const float* __restrict__ deg,
                     float* __restrict__ out, int nAtoms) {
    int m = blockIdx.x;
    int t = threadIdx.x;
    int lo = 0, hi = nAtoms;
    while (lo < hi) { int mid = (lo + hi) >> 1; if (mol_ids[mid] < m) lo = mid + 1; else hi = mid; }
    int start = lo;
    lo = start; hi = nAtoms;
    while (lo < hi) { int mid = (lo + hi) >> 1; if (mol_ids[mid] < m + 1) lo = mid + 1; else hi = mid; }
    int end = lo;
    float wsum = 0.f;
    for (int a = start; a < end; ++a) wsum += w_atoms[a];   // broadcast loads, ~50 iters
    float res = (wsum > 0.f) ? deg[m] * mol_sum[(size_t)m * 256 + t] / wsum : 0.f;
    out[m * 256 + t] = res;
}

// ---------- launch ----------
extern "C" void kernel_launch(void* const* d_in, const int* in_sizes, int n_in,
                              void* d_out, int out_size, void* d_ws, size_t ws_size,
                              hipStream_t stream) {
    const float* f_atoms = (const float*)d_in[0];
    const float* f_bonds = (const float*)d_in[1];
    const float* w_atoms = (const float*)d_in[2];
    const float* w_bonds = (const float*)d_in[3];
    const float* W_i     = (const float*)d_in[4];
    const float* W_h     = (const float*)d_in[5];
    const float* W_o     = (const float*)d_in[6];
    const float* b_o     = (const float*)d_in[7];
    const float* deg     = (const float*)d_in[8];
    const int*   a2b     = (const int*)d_in[9];
    const int*   b2a     = (const int*)d_in[10];
    const int*   b2revb  = (const int*)d_in[11];
    const int*   mol_ids = (const int*)d_in[12];
    float* out = (float*)d_out;

    const int nB = 250000, nA = 100000, nM = 2000;

    // ws layout (bytes):
    //  P0 @ 0     : inp bf16 [250k][256] = 128 MB (becomes msgB in-place after iter-1 GEMM)
    //  P1 @ 128M  : msgA bf16 [250k][256] = 128 MB
    //  P2 @ 256M  : mol_sum fp32 [2000][256] = 2.048 MB (was hid)
    //  P3 @ 384M  : amsg bf16 [100k][256] = 51.2 MB
    //  P4 @ 435.2M: Wt_i (81,920) | Wt_h (131,072) | Wt_o (229,376)
    char* ws = (char*)d_ws;
    u16* inp      = (u16*)(ws);
    u16* msgA     = (u16*)(ws + 128000000L);
    float* mol_sum = (float*)(ws + 256000000L);
    u16* amsg     = (u16*)(ws + 384000000L);
    u16* wt_i     = (u16*)(ws + 435200000L);
    u16* wt_h     = (u16*)(ws + 435200000L + 81920L);
    u16* wt_o     = (u16*)(ws + 435200000L + 81920L + 131072L);

    if (ws_size < 435642368UL) return;

    dim3 b256(256), b512(512), b1024(1024);
    // pack ranges: 40960 + 65536 + 114688 + 512000 = 733184 -> 2864 blocks
    pack_all<<<dim3(733184 / 256), b256, 0, stream>>>(
        W_i, W_h, W_o, wt_i, wt_h, wt_o, mol_sum);

    // GEMM1: inp = f_bonds @ W_i^T (fp32 A, conversion fused)
    gemm_in<<<dim3(977), b512, 0, stream>>>(f_bonds, wt_i, nB, inp);

    // gemm_mp grid: 256-row chunks, 8 XCDs * cpx * 2 halves
    const int nchB = (nB + 255) >> 8, cpxB = (nchB + 7) >> 3;
    dim3 gmp(8 * cpxB * 2);
    const int nchA = (nA + 255) >> 8, cpxA = (nchA + 7) >> 3;
    dim3 gro(8 * cpxA * 2);

    // iteration 0 (msg == relu(inp) on the fly everywhere)
    gather16<true><<<dim3((nA + 15) / 16), b256, 0, stream>>>(inp, a2b, w_bonds, amsg, nA);
    gemm_mp<true><<<gmp, b1024, 0, stream>>>(
        amsg, inp, b2a, b2revb, wt_h, nB, inp, msgA);

    // iteration 1
    gather16<false><<<dim3((nA + 15) / 16), b256, 0, stream>>>(msgA, a2b, w_bonds, amsg, nA);
    gemm_mp<false><<<gmp, b1024, 0, stream>>>(
        amsg, msgA, b2a, b2revb, wt_h, nB, inp, inp);   // msgB in-place over inp

    // final readout with fused aggregation
    gather16<false><<<dim3((nA + 15) / 16), b256, 0, stream>>>(inp /*msgB*/, a2b, w_bonds, amsg, nA);
    gemm_ro<<<gro, b512, 0, stream>>>(amsg, f_atoms, wt_o, nA, b_o, w_atoms, mol_ids, mol_sum);

    finalize_kernel<<<dim3(nM), b256, 0, stream>>>(mol_sum, w_atoms, mol_ids, deg, out, nA);
}

// Round 8
// 842.624 us; speedup vs baseline: 1.3070x; 1.0029x over previous
//
#include <hip/hip_runtime.h>
#include <hip/hip_bf16.h>

typedef unsigned short u16;
typedef __bf16 bf16x8v __attribute__((ext_vector_type(8)));
typedef float f32x4v __attribute__((ext_vector_type(4)));
typedef float f32x4u __attribute__((ext_vector_type(4))) __attribute__((aligned(4)));

// ---------- bf16 helpers (RNE) ----------
__device__ __forceinline__ float bf2f(u16 u) {
    union { float f; unsigned int i; } c; c.i = ((unsigned int)u) << 16; return c.f;
}
__device__ __forceinline__ u16 f2bf(float f) {
    union { float f; unsigned int i; } c; c.f = f;
    unsigned int i = c.i;
    unsigned int lsb = (i >> 16) & 1u;
    i += 0x7fffu + lsb;
    return (u16)(i >> 16);
}
__device__ __forceinline__ float lo16(unsigned u) { return bf2f((u16)(u & 0xffff)); }
__device__ __forceinline__ float hi16(unsigned u) { return bf2f((u16)(u >> 16)); }
__device__ __forceinline__ unsigned pack2(float lo, float hi) {
    return (unsigned)f2bf(lo) | ((unsigned)f2bf(hi) << 16);
}

// packed-bf16 bit tricks:
//   neg2:      x -> -x
//   relu_neg2: x -> -relu(x)
__device__ __forceinline__ unsigned neg2(unsigned u) { return u ^ 0x80008000u; }
__device__ __forceinline__ unsigned relu_neg2(unsigned u) {
    unsigned s = u & 0x80008000u;
    unsigned m = (s - (s >> 15)) | s;      // 0xffff per negative half
    return (u ^ 0x80008000u) & ~m;
}

// load 8 fp32 from rowp[k..k+7] (guarded, zero-padded), convert to bf16x8 fragment
__device__ __forceinline__ bf16x8v load_cvt8(const float* __restrict__ rowp, int k, int kmax) {
    union { unsigned u[4]; bf16x8v v; } r;
#pragma unroll
    for (int g = 0; g < 2; ++g) {
        int kk = k + g * 4;
        float f0, f1, f2, f3;
        if (kk + 3 < kmax) {
            f32x4u q = *(const f32x4u*)(rowp + kk);
            f0 = q.x; f1 = q.y; f2 = q.z; f3 = q.w;
        } else {
            f0 = (kk + 0 < kmax) ? rowp[kk + 0] : 0.f;
            f1 = (kk + 1 < kmax) ? rowp[kk + 1] : 0.f;
            f2 = (kk + 2 < kmax) ? rowp[kk + 2] : 0.f;
            f3 = (kk + 3 < kmax) ? rowp[kk + 3] : 0.f;
        }
        r.u[g * 2]     = pack2(f0, f1);
        r.u[g * 2 + 1] = pack2(f2, f3);
    }
    return r.v;
}

// ---------- all weight packing + mol_sum zeroing in ONE dispatch ----------
__global__ __launch_bounds__(256)
void pack_all(const float* __restrict__ W_i, const float* __restrict__ W_h,
              const float* __restrict__ W_o,
              u16* __restrict__ wti, u16* __restrict__ wth, u16* __restrict__ wto,
              float* __restrict__ mol_sum) {
    int idx = blockIdx.x * 256 + threadIdx.x;
    if (idx < 256 * 160) {
        int n = idx / 160, k = idx % 160;
        wti[idx] = f2bf(k < 147 ? W_i[k * 256 + n] : 0.f);
        return;
    }
    idx -= 256 * 160;
    if (idx < 256 * 256) {
        int n = idx / 256, k = idx % 256;
        wth[idx] = f2bf(W_h[k * 256 + n]);
        return;
    }
    idx -= 256 * 256;
    if (idx < 256 * 448) {
        int n = idx / 448, k = idx % 448;
        float v;
        if (k < 256)       v = W_o[(133 + k) * 256 + n];
        else if (k < 389)  v = W_o[(k - 256) * 256 + n];
        else               v = 0.f;
        wto[idx] = f2bf(v);
        return;
    }
    idx -= 256 * 448;
    if (idx < 2000 * 256) mol_sum[idx] = 0.f;
}

// ---------- gather (2 atoms/thread, 12 independent 16B loads in flight) ----------
template <bool RELU>
__global__ __launch_bounds__(256)
void gather16(const u16* __restrict__ msg, const int* __restrict__ a2b,
              const float* __restrict__ w_bonds, u16* __restrict__ out, int nAtoms) {
    int t = threadIdx.x;
    int g = t >> 5;                       // 0..7
    int co = (t & 31) * 8;
    int atom0 = blockIdx.x * 16 + g;
    int atom1 = atom0 + 8;
    if (atom1 >= nAtoms) { if (atom0 >= nAtoms) return; atom1 = atom0; }

    int bidx[12];
#pragma unroll
    for (int j = 0; j < 6; ++j) {
        bidx[j]     = a2b[atom0 * 6 + j];
        bidx[6 + j] = a2b[atom1 * 6 + j];
    }
    float w[12];
#pragma unroll
    for (int j = 0; j < 12; ++j) w[j] = w_bonds[bidx[j]];
    uint4 v[12];
#pragma unroll
    for (int j = 0; j < 12; ++j)
        v[j] = *(const uint4*)(msg + (size_t)bidx[j] * 256 + co);

    float a0[8] = {0,0,0,0,0,0,0,0}, a1[8] = {0,0,0,0,0,0,0,0};
#pragma unroll
    for (int j = 0; j < 6; ++j) {
        unsigned p[4] = {v[j].x, v[j].y, v[j].z, v[j].w};
        unsigned q[4] = {v[6+j].x, v[6+j].y, v[6+j].z, v[6+j].w};
#pragma unroll
        for (int c = 0; c < 4; ++c) {
            float m0 = lo16(p[c]), m1 = hi16(p[c]);
            float n0 = lo16(q[c]), n1 = hi16(q[c]);
            if (RELU) {
                m0 = fmaxf(m0, 0.f); m1 = fmaxf(m1, 0.f);
                n0 = fmaxf(n0, 0.f); n1 = fmaxf(n1, 0.f);
            }
            a0[c * 2]     += w[j] * m0;
            a0[c * 2 + 1] += w[j] * m1;
            a1[c * 2]     += w[6+j] * n0;
            a1[c * 2 + 1] += w[6+j] * n1;
        }
    }
    uint4 o0, o1;
    o0.x = pack2(a0[0], a0[1]); o0.y = pack2(a0[2], a0[3]);
    o0.z = pack2(a0[4], a0[5]); o0.w = pack2(a0[6], a0[7]);
    o1.x = pack2(a1[0], a1[1]); o1.y = pack2(a1[2], a1[3]);
    o1.z = pack2(a1[4], a1[5]); o1.w = pack2(a1[6], a1[7]);
    *(uint4*)(out + (size_t)atom0 * 256 + co) = o0;
    if (atom1 != atom0)
        *(uint4*)(out + (size_t)atom1 * 256 + co) = o1;
}

// ---------- GEMM1: inp = f_bonds(fp32, stride 147) @ W_i^T, conversion fused into A-load ----------
__global__ __launch_bounds__(512, 2)
void gemm_in(const float* __restrict__ A, const u16* __restrict__ Bt, int M,
             u16* __restrict__ out0) {
    constexpr int KPAD = 160, KMAX = 147, ASTR = 147;
    constexpr int LSTR = KPAD + 8;
    __shared__ u16 Bs[256 * LSTR];
    const int tid = threadIdx.x;
    const int wave = tid >> 6;
    const int lane = tid & 63;
    const int mrow = lane & 15;
    const int quad = lane >> 4;

    constexpr int KC = KPAD / 8;
    for (int i = tid; i < 256 * KC; i += 512) {
        int r = i / KC, kc = i % KC;
        *(uint4*)&Bs[r * LSTR + kc * 8] = *(const uint4*)&Bt[(size_t)r * KPAD + kc * 8];
    }
    __syncthreads();

    for (long chunk = blockIdx.x; chunk * 256 < (long)M; chunk += gridDim.x) {
        const long mbase = chunk * 256 + wave * 32;
        const float* rowp[2];
#pragma unroll
        for (int t = 0; t < 2; ++t) {
            long r = mbase + t * 16 + mrow;
            if (r >= M) r = M - 1;
            rowp[t] = A + r * ASTR;
        }

        f32x4v acc[2][16];
#pragma unroll
        for (int t = 0; t < 2; ++t)
#pragma unroll
            for (int j = 0; j < 16; ++j) acc[t][j] = (f32x4v){0.f, 0.f, 0.f, 0.f};

#pragma unroll 2
        for (int k0 = 0; k0 < KPAD; k0 += 32) {
            bf16x8v a_frag[2];
#pragma unroll
            for (int t = 0; t < 2; ++t)
                a_frag[t] = load_cvt8(rowp[t], k0 + quad * 8, KMAX);
#pragma unroll
            for (int jg = 0; jg < 4; ++jg) {
                bf16x8v b_frag[4];
#pragma unroll
                for (int j4 = 0; j4 < 4; ++j4)
                    b_frag[j4] = *(const bf16x8v*)&Bs[((jg * 4 + j4) * 16 + mrow) * LSTR + k0 + quad * 8];
#pragma unroll
                for (int t = 0; t < 2; ++t)
#pragma unroll
                    for (int j4 = 0; j4 < 4; ++j4)
                        acc[t][jg * 4 + j4] = __builtin_amdgcn_mfma_f32_16x16x32_bf16(
                            a_frag[t], b_frag[j4], acc[t][jg * 4 + j4], 0, 0, 0);
            }
        }

#pragma unroll
        for (int t = 0; t < 2; ++t)
#pragma unroll
            for (int r = 0; r < 4; ++r) {
                long grow = mbase + t * 16 + quad * 4 + r;
                if (grow < M)
#pragma unroll
                    for (int j = 0; j < 16; ++j)
                        out0[(size_t)grow * 256 + j * 16 + mrow] = f2bf(acc[t][j][r]);
            }
    }
}

// ---------- fused message-passing GEMM ----------
// msg_new[b][:] = relu( inp[b] + (amsg[b2a[b]] - relu?(msgsrc[b2revb[b]])) @ Wh^T )
// R6 structure (1024 thr, 256 bonds x 128-col half, XCD-paired halves) plus:
//  * depth-4 static-unrolled gather pipeline (16 x 16B loads in flight/thread,
//    each row's 512B requested in a tight burst -> DRAM page locality)
//  * LDS-transpose epilogue: acc staged fp32 into the retired B-LDS, then
//    16B/lane contiguous inp-read + out-write (was 64 scalar 2B ops/thread ->
//    the dominant VMEM-transaction cost per R7 analysis)
template <bool RELUV>
__global__ __launch_bounds__(1024, 4)
void gemm_mp(const u16* __restrict__ amsg, const u16* __restrict__ msgsrc,
             const int* __restrict__ b2a, const int* __restrict__ b2revb,
             const u16* __restrict__ Bt, int M,
             const u16* __restrict__ inp, u16* __restrict__ out0) {
    constexpr int KPAD = 256;
    constexpr int LSTR = KPAD + 8;
    constexpr int NROWS = 128;                 // N-half per block
    __shared__ u16 Bs[NROWS * LSTR];           // 67584 B (reused as fp32 [128][132] in epilogue)
    const int tid = threadIdx.x;
    const int wave = tid >> 6;                 // 0..15, 16 bonds each
    const int lane = tid & 63;
    const int mrow = lane & 15;
    const int quad = lane >> 4;

    const int nch = (M + 255) >> 8;            // 256-row chunks
    const int cpx = (nch + 7) >> 3;            // chunks per XCD
    const int bid = blockIdx.x;
    const int xcd = bid & 7;
    const int seq = bid >> 3;
    const long chunk = (long)xcd * cpx + (seq >> 1);
    if (chunk >= nch) return;                  // uniform pre-barrier exit
    const int nbase = (seq & 1) * NROWS;

    for (int i = tid; i < NROWS * 32; i += 1024) {
        int r = i >> 5, kc = i & 31;
        *(uint4*)&Bs[r * LSTR + kc * 8] = *(const uint4*)&Bt[(size_t)(nbase + r) * KPAD + kc * 8];
    }
    __syncthreads();

    const long cbase = chunk * 256;
    const long mbase = cbase + wave * 16;
    long b = mbase + mrow;
    if (b >= M) b = M - 1;
    const size_t soff = (size_t)b2a[b] * 256 + quad * 8;
    const size_t roff = (size_t)b2revb[b] * 256 + quad * 8;

    f32x4v acc[8];
#pragma unroll
    for (int j = 0; j < 8; ++j) acc[j] = (f32x4v){0.f, 0.f, 0.f, 0.f};

    // depth-4 software pipeline over 8 k-chunks (fully unrolled: static indices)
    uint4 va[8], vr[8];
#pragma unroll
    for (int kk = 0; kk < 4; ++kk) {
        va[kk] = *(const uint4*)&amsg[soff + kk * 32];
        vr[kk] = *(const uint4*)&msgsrc[roff + kk * 32];
    }
#pragma unroll
    for (int kk = 0; kk < 8; ++kk) {
        if (kk < 4) {
            va[kk + 4] = *(const uint4*)&amsg[soff + (kk + 4) * 32];
            vr[kk + 4] = *(const uint4*)&msgsrc[roff + (kk + 4) * 32];
        }
        const int k0 = kk * 32;
        union { uint4 q; bf16x8v v; } ua, ur;
        ua.q = va[kk];
        uint4 w = vr[kk];
        if (RELUV) {
            ur.q.x = relu_neg2(w.x); ur.q.y = relu_neg2(w.y);
            ur.q.z = relu_neg2(w.z); ur.q.w = relu_neg2(w.w);
        } else {
            ur.q.x = neg2(w.x); ur.q.y = neg2(w.y);
            ur.q.z = neg2(w.z); ur.q.w = neg2(w.w);
        }
#pragma unroll
        for (int j = 0; j < 8; ++j) {
            bf16x8v b_frag = *(const bf16x8v*)&Bs[(j * 16 + mrow) * LSTR + k0 + quad * 8];
            acc[j] = __builtin_amdgcn_mfma_f32_16x16x32_bf16(ua.v, b_frag, acc[j], 0, 0, 0);
            acc[j] = __builtin_amdgcn_mfma_f32_16x16x32_bf16(ur.v, b_frag, acc[j], 0, 0, 0);
        }
    }

    // ---- LDS-transpose epilogue ----
    // Es = fp32 [128 rows][132 stride] = 67584 B exactly (reuses Bs).
    // pass p: waves p*8..p*8+7 dump acc for bonds [p*128, p*128+128); then all
    // 1024 threads store: thread -> (row = s*64 + tid>>4, 8 cols = (tid&15)*8),
    // 16B contiguous global read+write per lane (256B per 16-lane row group).
    float* Es = (float*)Bs;
#pragma unroll 1
    for (int p = 0; p < 2; ++p) {
        __syncthreads();                       // Bs k-loop reads / prev pass reads done
        if ((wave >> 3) == p) {
            const int lr0 = (wave & 7) * 16 + quad * 4;
#pragma unroll
            for (int r = 0; r < 4; ++r)
#pragma unroll
                for (int j = 0; j < 8; ++j)
                    Es[(lr0 + r) * 132 + j * 16 + mrow] = acc[j][r];
        }
        __syncthreads();
#pragma unroll
        for (int s = 0; s < 2; ++s) {
            const int lr = s * 64 + (tid >> 4);
            const int c0 = (tid & 15) * 8;
            const long g = cbase + p * 128 + lr;
            if (g < M) {
                const size_t base = (size_t)g * 256 + nbase + c0;
                uint4 iv = *(const uint4*)&inp[base];
                float e0 = Es[lr * 132 + c0 + 0], e1 = Es[lr * 132 + c0 + 1];
                float e2 = Es[lr * 132 + c0 + 2], e3 = Es[lr * 132 + c0 + 3];
                float e4 = Es[lr * 132 + c0 + 4], e5 = Es[lr * 132 + c0 + 5];
                float e6 = Es[lr * 132 + c0 + 6], e7 = Es[lr * 132 + c0 + 7];
                float s0 = lo16(iv.x) + e0, s1 = hi16(iv.x) + e1;
                float s2 = lo16(iv.y) + e2, s3 = hi16(iv.y) + e3;
                float s4 = lo16(iv.z) + e4, s5 = hi16(iv.z) + e5;
                float s6 = lo16(iv.w) + e6, s7 = hi16(iv.w) + e7;
                uint4 ov;
                ov.x = pack2(s0 > 0.f ? s0 : 0.f, s1 > 0.f ? s1 : 0.f);
                ov.y = pack2(s2 > 0.f ? s2 : 0.f, s3 > 0.f ? s3 : 0.f);
                ov.z = pack2(s4 > 0.f ? s4 : 0.f, s5 > 0.f ? s5 : 0.f);
                ov.w = pack2(s6 > 0.f ? s6 : 0.f, s7 > 0.f ? s7 : 0.f);
                *(uint4*)&out0[base] = ov;
            }
        }
    }
}

// ---------- readout GEMM with FUSED per-molecule aggregation (R7, unchanged) ----------
__global__ __launch_bounds__(512, 4)
void gemm_ro(const u16* __restrict__ A1, const float* __restrict__ A2,
             const u16* __restrict__ Bt, int M,
             const float* __restrict__ bias,
             const float* __restrict__ w_atoms, const int* __restrict__ mol_ids,
             float* __restrict__ mol_sum) {
    constexpr int KPAD = 448, KSPLIT = 256, K2 = 192, KMAX2 = 133;
    constexpr int LSTR = KSPLIT + 8;           // stage-1 stride (264)
    constexpr int LSTR2 = K2 + 8;              // stage-2 stride (200)
    constexpr int NROWS = 128;
    __shared__ u16 Bs[NROWS * LSTR];           // 67584 B, reused by stage 2
    const int tid = threadIdx.x;
    const int wave = tid >> 6;
    const int lane = tid & 63;
    const int mrow = lane & 15;
    const int quad = lane >> 4;

    const int nch = (M + 255) >> 8;
    const int cpx = (nch + 7) >> 3;
    const int bid = blockIdx.x;
    const int xcd = bid & 7;
    const int seq = bid >> 3;
    const long chunk = (long)xcd * cpx + (seq >> 1);
    if (chunk >= nch) return;
    const int nbase = (seq & 1) * NROWS;

    for (int i = tid; i < NROWS * 32; i += 512) {
        int r = i >> 5, kc = i & 31;
        *(uint4*)&Bs[r * LSTR + kc * 8] =
            *(const uint4*)&Bt[(size_t)(nbase + r) * KPAD + kc * 8];
    }
    __syncthreads();

    const long mbase = chunk * 256 + wave * 32;
    long row[2];
#pragma unroll
    for (int t = 0; t < 2; ++t) {
        long r = mbase + t * 16 + mrow;
        if (r >= M) r = M - 1;
        row[t] = r;
    }

    f32x4v acc[2][8];
#pragma unroll
    for (int t = 0; t < 2; ++t)
#pragma unroll
        for (int j = 0; j < 8; ++j) acc[t][j] = (f32x4v){0.f, 0.f, 0.f, 0.f};

#pragma unroll 2
    for (int k0 = 0; k0 < KSPLIT; k0 += 32) {
        bf16x8v a_frag[2];
#pragma unroll
        for (int t = 0; t < 2; ++t)
            a_frag[t] = *(const bf16x8v*)&A1[row[t] * KSPLIT + k0 + quad * 8];
#pragma unroll
        for (int jg = 0; jg < 2; ++jg) {
            bf16x8v b_frag[4];
#pragma unroll
            for (int j4 = 0; j4 < 4; ++j4)
                b_frag[j4] = *(const bf16x8v*)&Bs[((jg * 4 + j4) * 16 + mrow) * LSTR + k0 + quad * 8];
#pragma unroll
            for (int t = 0; t < 2; ++t)
#pragma unroll
                for (int j4 = 0; j4 < 4; ++j4)
                    acc[t][jg * 4 + j4] = __builtin_amdgcn_mfma_f32_16x16x32_bf16(
                        a_frag[t], b_frag[j4], acc[t][jg * 4 + j4], 0, 0, 0);
        }
    }

    __syncthreads();
    for (int i = tid; i < NROWS * 24; i += 512) {
        int r = i / 24, kc = i % 24;
        *(uint4*)&Bs[r * LSTR2 + kc * 8] =
            *(const uint4*)&Bt[(size_t)(nbase + r) * KPAD + KSPLIT + kc * 8];
    }
    __syncthreads();

#pragma unroll 2
    for (int k0 = 0; k0 < K2; k0 += 32) {
        bf16x8v a_frag[2];
#pragma unroll
        for (int t = 0; t < 2; ++t)
            a_frag[t] = load_cvt8(A2 + row[t] * KMAX2, k0 + quad * 8, KMAX2);
#pragma unroll
        for (int jg = 0; jg < 2; ++jg) {
            bf16x8v b_frag[4];
#pragma unroll
            for (int j4 = 0; j4 < 4; ++j4)
                b_frag[j4] = *(const bf16x8v*)&Bs[((jg * 4 + j4) * 16 + mrow) * LSTR2 + k0 + quad * 8];
#pragma unroll
            for (int t = 0; t < 2; ++t)
#pragma unroll
                for (int j4 = 0; j4 < 4; ++j4)
                    acc[t][jg * 4 + j4] = __builtin_amdgcn_mfma_f32_16x16x32_bf16(
                        a_frag[t], b_frag[j4], acc[t][jg * 4 + j4], 0, 0, 0);
        }
    }

#pragma unroll
    for (int t = 0; t < 2; ++t) {
        float w4[4]; int m4[4]; bool ok4[4];
#pragma unroll
        for (int r = 0; r < 4; ++r) {
            long grow = mbase + t * 16 + quad * 4 + r;
            ok4[r] = (grow < M);
            long gr = ok4[r] ? grow : (M - 1);
            w4[r] = w_atoms[gr];
            m4[r] = mol_ids[gr];
        }
#pragma unroll
        for (int j = 0; j < 8; ++j) {
            int gcol = nbase + j * 16 + mrow;
            float b = bias[gcol];
            float vsum = 0.f;
            int prev = -1;
#pragma unroll
            for (int r = 0; r < 4; ++r) {
                if (ok4[r]) {
                    float s = acc[t][j][r] + b;
                    s = s > 0.f ? s : 0.f;
                    float v = s * w4[r];
                    if (m4[r] != prev) {
                        if (prev >= 0) atomicAdd(&mol_sum[(size_t)prev * 256 + gcol], vsum);
                        vsum = 0.f;
                        prev = m4[r];
                    }
                    vsum += v;
                }
            }
            if (prev >= 0) atomicAdd(&mol_sum[(size_t)prev * 256 + gcol], vsum);
        }
    }
}

// ---------- finalize: out[m] = deg[m] * mol_sum[m] / wsum[m] ----------
__global__ __launch_bounds__(256)
void finalize_kernel(const float* __restrict__ mol_sum, const float* __restrict__ w_atoms,
                     const int* __restrict__ mol_ids, const float* __restrict__ deg,
                     float* __restrict__ out, int nAtoms) {
    int m = blockIdx.x;
    int t = threadIdx.x;
    int lo = 0, hi = nAtoms;
    while (lo < hi) { int mid = (lo + hi) >> 1; if (mol_ids[mid] < m) lo = mid + 1; else hi = mid; }
    int start = lo;
    lo = start; hi = nAtoms;
    while (lo < hi) { int mid = (lo + hi) >> 1; if (mol_ids[mid] < m + 1) lo = mid + 1; else hi = mid; }
    int end = lo;
    float wsum = 0.f;
    for (int a = start; a < end; ++a) wsum += w_atoms[a];
    float res = (wsum > 0.f) ? deg[m] * mol_sum[(size_t)m * 256 + t] / wsum : 0.f;
    out[m * 256 + t] = res;
}

// ---------- launch ----------
extern "C" void kernel_launch(void* const* d_in, const int* in_sizes, int n_in,
                              void* d_out, int out_size, void* d_ws, size_t ws_size,
                              hipStream_t stream) {
    const float* f_atoms = (const float*)d_in[0];
    const float* f_bonds = (const float*)d_in[1];
    const float* w_atoms = (const float*)d_in[2];
    const float* w_bonds = (const float*)d_in[3];
    const float* W_i     = (const float*)d_in[4];
    const float* W_h     = (const float*)d_in[5];
    const float* W_o     = (const float*)d_in[6];
    const float* b_o     = (const float*)d_in[7];
    const float* deg     = (const float*)d_in[8];
    const int*   a2b     = (const int*)d_in[9];
    const int*   b2a     = (const int*)d_in[10];
    const int*   b2revb  = (const int*)d_in[11];
    const int*   mol_ids = (const int*)d_in[12];
    float* out = (float*)d_out;

    const int nB = 250000, nA = 100000, nM = 2000;

    char* ws = (char*)d_ws;
    u16* inp       = (u16*)(ws);
    u16* msgA      = (u16*)(ws + 128000000L);
    float* mol_sum = (float*)(ws + 256000000L);
    u16* amsg      = (u16*)(ws + 384000000L);
    u16* wt_i      = (u16*)(ws + 435200000L);
    u16* wt_h      = (u16*)(ws + 435200000L + 81920L);
    u16* wt_o      = (u16*)(ws + 435200000L + 81920L + 131072L);

    if (ws_size < 435642368UL) return;

    dim3 b256(256), b512(512), b1024(1024);
    pack_all<<<dim3(733184 / 256), b256, 0, stream>>>(
        W_i, W_h, W_o, wt_i, wt_h, wt_o, mol_sum);

    gemm_in<<<dim3(977), b512, 0, stream>>>(f_bonds, wt_i, nB, inp);

    const int nchB = (nB + 255) >> 8, cpxB = (nchB + 7) >> 3;
    dim3 gmp(8 * cpxB * 2);
    const int nchA = (nA + 255) >> 8, cpxA = (nchA + 7) >> 3;
    dim3 gro(8 * cpxA * 2);

    // iteration 0 (msg == relu(inp) on the fly everywhere)
    gather16<true><<<dim3((nA + 15) / 16), b256, 0, stream>>>(inp, a2b, w_bonds, amsg, nA);
    gemm_mp<true><<<gmp, b1024, 0, stream>>>(
        amsg, inp, b2a, b2revb, wt_h, nB, inp, msgA);

    // iteration 1
    gather16<false><<<dim3((nA + 15) / 16), b256, 0, stream>>>(msgA, a2b, w_bonds, amsg, nA);
    gemm_mp<false><<<gmp, b1024, 0, stream>>>(
        amsg, msgA, b2a, b2revb, wt_h, nB, inp, inp);   // msgB in-place over inp

    // final readout with fused aggregation
    gather16<false><<<dim3((nA + 15) / 16), b256, 0, stream>>>(inp /*msgB*/, a2b, w_bonds, amsg, nA);
    gemm_ro<<<gro, b512, 0, stream>>>(amsg, f_atoms, wt_o, nA, b_o, w_atoms, mol_ids, mol_sum);

    finalize_kernel<<<dim3(nM), b256, 0, stream>>>(mol_sum, w_atoms, mol_ids, deg, out, nA);
}